// Round 15
// baseline (421.514 us; speedup 1.0000x reference)
//
#include <hip/hip_runtime.h>

// CrossAttention MI355X — round 15 (= round-14 design + restored hring zero-
// init: halo cols idx 0 and 193..195 must start zero; GEMM only writes 1..192).
// k_conv_all: single-barrier mixed phases, 2-slot h-ring + double-buffered
// xrow (155.1KB LDS); dwise keeps h rows r-3, r-2 in registers (rotation) and
// reads only the newest h row from the ring.
//  k_conv_all      : q/k/v = in + dw3x3(pw @ in)
//  k_gram          : G[b,h] = q @ k^T    (32x32x16 MFMA)
//  k_attn          : norms + softmax + M[b] = proj @ attn_blockdiag
//  k_gemm          : out = M[b] @ v      (f32 direct epilogue)

#define B_  8
#define C_  96
#define W_  192
#define HW_ 36864
#define NB_ 32     // row-bands per image (6 rows each)

typedef __attribute__((ext_vector_type(8)))  short short8;
typedef __attribute__((ext_vector_type(4)))  float f32x4;
typedef __attribute__((ext_vector_type(16))) float f32x16;

__device__ __forceinline__ unsigned short f2b(float f){
  unsigned u = __float_as_uint(f);
  u += 0x7fffu + ((u >> 16) & 1u);
  return (unsigned short)(u >> 16);
}
__device__ __forceinline__ float blo(unsigned u){ return __uint_as_float(u << 16); }
__device__ __forceinline__ float bhi(unsigned u){ return __uint_as_float(u & 0xffff0000u); }

// Barrier waiting only on LDS ops (lgkmcnt), not global stores (vmcnt).
__device__ __forceinline__ void barrier_lds(){
  asm volatile("s_waitcnt lgkmcnt(0)\n\ts_barrier" ::: "memory");
}

// ---------------- k_conv_all: out = in + dw3x3(pw @ in) ----------------------
// grid (32 bands, 8 b, 3 conv), block 768 (12 waves), 155.1KB LDS (1 blk/CU).
// Phase P(r), r = r0-1 .. r0+7, ONE barrier each:
//   issue stage-loads(r+1) -> GEMM(r): xrow[slr] -> hring[slr]  (or zero slot)
//   -> stage-write(r+1) into xrow[slr^1] -> read h row r-1 from hring[slr^1]
//   -> dwise(r-2) from reg rows (r-3, r-2) + new row (r-1) -> rotate.
__global__ __launch_bounds__(768, 1)
void k_conv_all(const float* __restrict__ x0, const float* __restrict__ x1,
                const float* __restrict__ x2,
                const float* __restrict__ pw0, const float* __restrict__ pw1,
                const float* __restrict__ pw2,
                const float* __restrict__ dw0, const float* __restrict__ dw1,
                const float* __restrict__ dw2,
                unsigned short* __restrict__ o0, unsigned short* __restrict__ o1,
                unsigned short* __restrict__ o2,
                float* __restrict__ n0, float* __restrict__ n1)
{
  __shared__ unsigned short xrow[2][192 * 104];   // 79,872 B [buf][pix][ch]
  __shared__ unsigned short hring[2][96 * 196];   // 75,264 B [slot][ch][1+col]

  const int t = threadIdx.x, lane = t & 63, wv = t >> 6;
  const int band = blockIdx.x, b = blockIdx.y, cid = blockIdx.z;
  const float* xsrc = (cid == 0) ? x0 : (cid == 1) ? x1 : x2;
  const float* pw   = (cid == 0) ? pw0 : (cid == 1) ? pw1 : pw2;
  const float* dwt  = (cid == 0) ? dw0 : (cid == 1) ? dw1 : dw2;
  unsigned short* outq = (cid == 0) ? o0 : (cid == 1) ? o1 : o2;
  float* nrm = (cid == 0) ? n0 : (cid == 1) ? n1 : nullptr;

  const int r0 = band * 6;
  const int l15 = lane & 15, l4 = lane >> 4;
  const int mtg = wv % 6, ntg = wv / 6;           // ntg 0..1
  const float* xb = xsrc + (size_t)b * C_ * HW_;

  // staging task decomposition: 2304 = 768 x 3 exactly (48cp x 48pg)
  int scp[3], spg[3];
  #pragma unroll
  for (int i = 0; i < 3; ++i){
    const int idx = i * 768 + t;
    scp[i] = idx / 48; spg[i] = idx - scp[i] * 48;
  }

  // pw A-frags in registers: single m-tile (16 rows) x 3 k-steps
  short8 afrag[3];
  #pragma unroll
  for (int ks = 0; ks < 3; ++ks){
    const int m = mtg * 16 + l15;
    const float* ap = pw + m * 96 + ks * 32 + l4 * 8;
    const float4 f0 = *(const float4*)ap;
    const float4 f1 = *(const float4*)(ap + 4);
    union { short8 v; unsigned short u[8]; } tmp;
    tmp.u[0]=f2b(f0.x); tmp.u[1]=f2b(f0.y); tmp.u[2]=f2b(f0.z); tmp.u[3]=f2b(f0.w);
    tmp.u[4]=f2b(f1.x); tmp.u[5]=f2b(f1.y); tmp.u[6]=f2b(f1.z); tmp.u[7]=f2b(f1.w);
    afrag[ks] = tmp.v;
  }

  // zero BOTH ring slots once: halo cols (idx 0, 193..195) must start zero —
  // the GEMM only ever writes idx 1..192.  4704 uint4 = 75,264 B.
  {
    uint4* p = (uint4*)&hring[0][0];
    for (int i = t; i < 4704; i += 768) p[i] = make_uint4(0,0,0,0);
  }

  float ssq[8];
  #pragma unroll
  for (int i = 0; i < 8; ++i) ssq[i] = 0.f;

  // rotation state: packed h rows (uint2.x, uint2.y, ext dword) per channel
  unsigned h0lo[8], h0hi[8], h0ex[8];   // row r-3 at dwise time
  unsigned h1lo[8], h1hi[8], h1ex[8];   // row r-2

  auto stage_load = [&](int rs, float4* fa, float4* fb){
    #pragma unroll
    for (int i = 0; i < 3; ++i){
      const float* xp = xb + (size_t)(2*scp[i]) * HW_ + (size_t)rs * W_ + 4*spg[i];
      fa[i] = *(const float4*)xp;
      fb[i] = *(const float4*)(xp + HW_);
    }
  };
  auto stage_write = [&](int buf, const float4* fa, const float4* fb){
    unsigned short* xw = &xrow[buf][0];
    #pragma unroll
    for (int i = 0; i < 3; ++i){
      const int pg = spg[i];
      const unsigned pk0 = (unsigned)f2b(fa[i].x) | ((unsigned)f2b(fb[i].x) << 16);
      const unsigned pk1 = (unsigned)f2b(fa[i].y) | ((unsigned)f2b(fb[i].y) << 16);
      const unsigned pk2 = (unsigned)f2b(fa[i].z) | ((unsigned)f2b(fb[i].z) << 16);
      const unsigned pk3 = (unsigned)f2b(fa[i].w) | ((unsigned)f2b(fb[i].w) << 16);
      const int s = (pg >> 1) & 3;                 // XOR-barrel bank spread
      const unsigned a0 = (s & 1) ? pk1 : pk0;
      const unsigned a1 = (s & 1) ? pk0 : pk1;
      const unsigned a2 = (s & 1) ? pk3 : pk2;
      const unsigned a3 = (s & 1) ? pk2 : pk3;
      const unsigned q0 = (s & 2) ? a2 : a0;
      const unsigned q1 = (s & 2) ? a3 : a1;
      const unsigned q2 = (s & 2) ? a0 : a2;
      const unsigned q3 = (s & 2) ? a1 : a3;
      unsigned short* basep = xw + (4*pg) * 104 + 2*scp[i];
      *(unsigned*)(basep + ((0 ^ s) * 104)) = q0;
      *(unsigned*)(basep + ((1 ^ s) * 104)) = q1;
      *(unsigned*)(basep + ((2 ^ s) * 104)) = q2;
      *(unsigned*)(basep + ((3 ^ s) * 104)) = q3;
    }
  };

  // prologue: stage row r0-1 into xrow[(r0+3)&1] if in image
  if (r0 - 1 >= 0){
    float4 fa[3], fb[3];
    stage_load(r0 - 1, fa, fb);
    stage_write((r0 + 3) & 1, fa, fb);
  }
  barrier_lds();

  #pragma unroll 1
  for (int r = r0 - 1; r <= r0 + 7; ++r){
    const int slr = (r + 4) & 1;           // xrow buf and ring slot for row r
    const int rs = r + 1;
    const bool do_stage = (rs <= r0 + 6) && (rs < 192);
    float4 sfa[3], sfb[3];
    if (do_stage) stage_load(rs, sfa, sfb);   // issue early

    // ---- GEMM row r (or zero slot)
    if (r <= r0 + 6){
      if (r >= 0 && r < 192){
        const unsigned short* xr = &xrow[slr][0];
        f32x4 acc[6];
        #pragma unroll
        for (int nt = 0; nt < 6; ++nt){
          acc[nt][0]=0.f; acc[nt][1]=0.f; acc[nt][2]=0.f; acc[nt][3]=0.f;
        }
        #pragma unroll
        for (int ks = 0; ks < 3; ++ks){
          #pragma unroll
          for (int nt = 0; nt < 6; ++nt){
            const short8 bv = *(const short8*)(xr + (ntg*96 + nt*16 + l15) * 104 + ks*32 + l4*8);
            acc[nt] = __builtin_amdgcn_mfma_f32_16x16x32_bf16(afrag[ks], bv, acc[nt], 0, 0, 0);
          }
        }
        unsigned short* hs = &hring[slr][0];
        #pragma unroll
        for (int nt = 0; nt < 6; ++nt)
          #pragma unroll
          for (int reg = 0; reg < 4; ++reg){
            const int m = mtg*16 + l4*4 + reg;            // out-ch
            const int n = ntg*96 + nt*16 + l15;           // pix col
            hs[m * 196 + 1 + n] = f2b(acc[nt][reg]);
          }
      } else {
        uint4* p = (uint4*)&hring[slr][0];
        for (int i = t; i < 2352; i += 768) p[i] = make_uint4(0,0,0,0);
      }
    }

    // ---- stage-write(r+1) (frees stage regs before dwise)
    if (do_stage) stage_write(slr ^ 1, sfa, sfb);

    // ---- read newest h row (r-1) + dwise(r-2) + rotate
    if (r >= r0){
      unsigned nlo[8], nhi[8], nex[8];
      if (lane < 48){
        const int g = lane;
        const unsigned short* hb_ = &hring[slr ^ 1][0];   // row r-1
        #pragma unroll
        for (int cc = 0; cc < 8; ++cc){
          const unsigned short* hp = hb_ + (wv*8 + cc) * 196 + 4*g;
          const uint2 ua = *(const uint2*)hp;             // imgcols 4g-1..4g+2
          nlo[cc] = ua.x; nhi[cc] = ua.y;
          nex[cc] = *(const unsigned*)(hp + 4);           // imgcols 4g+3,4g+4
        }
        if (r >= r0 + 2){
          const int rr = r - 2;                           // output row
          float4 xr_[8];                                  // hoisted residual
          const float* xrp = xb + (size_t)rr * W_ + 4*g;
          #pragma unroll
          for (int cc = 0; cc < 8; ++cc)
            xr_[cc] = *(const float4*)(xrp + (size_t)(wv*8 + cc) * HW_);
          #pragma unroll
          for (int cc = 0; cc < 8; ++cc){
            const int chs = __builtin_amdgcn_readfirstlane(wv*8 + cc);
            float wgt[9];
            #pragma unroll
            for (int i = 0; i < 9; ++i) wgt[i] = dwt[chs * 9 + i];   // s_load
            float hv[3][6];
            hv[0][0]=blo(h0lo[cc]); hv[0][1]=bhi(h0lo[cc]); hv[0][2]=blo(h0hi[cc]);
            hv[0][3]=bhi(h0hi[cc]); hv[0][4]=blo(h0ex[cc]); hv[0][5]=bhi(h0ex[cc]);
            hv[1][0]=blo(h1lo[cc]); hv[1][1]=bhi(h1lo[cc]); hv[1][2]=blo(h1hi[cc]);
            hv[1][3]=bhi(h1hi[cc]); hv[1][4]=blo(h1ex[cc]); hv[1][5]=bhi(h1ex[cc]);
            hv[2][0]=blo(nlo[cc]);  hv[2][1]=bhi(nlo[cc]);  hv[2][2]=blo(nhi[cc]);
            hv[2][3]=bhi(nhi[cc]);  hv[2][4]=blo(nex[cc]);  hv[2][5]=bhi(nex[cc]);
            float o[4] = {xr_[cc].x, xr_[cc].y, xr_[cc].z, xr_[cc].w};
            #pragma unroll
            for (int j = 0; j < 4; ++j){
              float s = o[j];
              #pragma unroll
              for (int d = 0; d < 3; ++d){
                s = fmaf(wgt[d*3+0], hv[d][j],   s);
                s = fmaf(wgt[d*3+1], hv[d][j+1], s);
                s = fmaf(wgt[d*3+2], hv[d][j+2], s);
              }
              o[j] = s;
              ssq[cc] = fmaf(s, s, ssq[cc]);
            }
            const size_t cb = (size_t)(b * C_ + chs) * HW_ + (size_t)rr * W_ + 4*g;
            const unsigned p0 = (unsigned)f2b(o[0]) | ((unsigned)f2b(o[1]) << 16);
            const unsigned p1 = (unsigned)f2b(o[2]) | ((unsigned)f2b(o[3]) << 16);
            *(uint2*)(outq + cb) = make_uint2(p0, p1);
          }
        }
        #pragma unroll
        for (int cc = 0; cc < 8; ++cc){                   // rotate
          h0lo[cc]=h1lo[cc]; h0hi[cc]=h1hi[cc]; h0ex[cc]=h1ex[cc];
          h1lo[cc]=nlo[cc];  h1hi[cc]=nhi[cc];  h1ex[cc]=nex[cc];
        }
      }
    }
    barrier_lds();
  }

  if (nrm){
    #pragma unroll
    for (int cc = 0; cc < 8; ++cc){
      float s = ssq[cc];                     // lanes 48..63 contribute 0
      #pragma unroll
      for (int off = 32; off; off >>= 1) s += __shfl_xor(s, off);
      if (lane == 0)
        nrm[((size_t)b * NB_ + band) * C_ + wv * 8 + cc] = s;
    }
  }
}

// ---------------- k_gemm: out[96][36864] = M(96x96,per-b) @ v ----------------
__global__ __launch_bounds__(256, 2)
void k_gemm(const unsigned short* __restrict__ Bsrc, const float* __restrict__ Asrc,
            float* __restrict__ Dst)
{
  __shared__ unsigned short xT[256 * 104];   // 53,248 B  [pix][ch]
  __shared__ unsigned short aw[96 * 104];    // 19,968 B  [m][k]
  const int t = threadIdx.x;
  const int b = blockIdx.y;
  const int p0 = blockIdx.x * 256;
  const int lane = t & 63, w = t >> 6;
  const int l15 = lane & 15, l4 = lane >> 4;

  const float* Ab = Asrc + b * C_ * C_;
  #pragma unroll
  for (int j = 0; j < 18; ++j){
    const int pi = j * 256 + t;
    const int row = pi / 48, c2 = (pi - row * 48) * 2;
    const float a0 = Ab[row * 96 + c2], a1 = Ab[row * 96 + c2 + 1];
    *(unsigned*)(aw + row * 104 + c2) = (unsigned)f2b(a0) | ((unsigned)f2b(a1) << 16);
  }
  #pragma unroll 1
  for (int i = 0; i < 12; ++i){
    const int idx = i * 256 + t;
    const int cp = idx >> 6, pg = idx & 63;
    const unsigned short* vp = Bsrc + (size_t)b * C_ * HW_ + (size_t)(2*cp) * HW_ + p0 + 4*pg;
    const uint2 ua = *(const uint2*)vp;          // 4 px of ch 2cp
    const uint2 ub = *(const uint2*)(vp + HW_);  // 4 px of ch 2cp+1
    const unsigned pk0 = (ua.x & 0xffffu) | (ub.x << 16);
    const unsigned pk1 = (ua.x >> 16)     | (ub.x & 0xffff0000u);
    const unsigned pk2 = (ua.y & 0xffffu) | (ub.y << 16);
    const unsigned pk3 = (ua.y >> 16)     | (ub.y & 0xffff0000u);
    const int s = (pg >> 1) & 3;
    const unsigned a0 = (s & 1) ? pk1 : pk0;
    const unsigned a1 = (s & 1) ? pk0 : pk1;
    const unsigned a2 = (s & 1) ? pk3 : pk2;
    const unsigned a3 = (s & 1) ? pk2 : pk3;
    const unsigned q0 = (s & 2) ? a2 : a0;
    const unsigned q1 = (s & 2) ? a3 : a1;
    const unsigned q2 = (s & 2) ? a0 : a2;
    const unsigned q3 = (s & 2) ? a1 : a3;
    unsigned short* basep = xT + (4*pg) * 104 + 2*cp;
    *(unsigned*)(basep + ((0 ^ s) * 104)) = q0;
    *(unsigned*)(basep + ((1 ^ s) * 104)) = q1;
    *(unsigned*)(basep + ((2 ^ s) * 104)) = q2;
    *(unsigned*)(basep + ((3 ^ s) * 104)) = q3;
  }
  __syncthreads();

  f32x4 acc[6][4];
  #pragma unroll
  for (int i = 0; i < 6; ++i)
    #pragma unroll
    for (int j = 0; j < 4; ++j){ acc[i][j][0]=0.f; acc[i][j][1]=0.f; acc[i][j][2]=0.f; acc[i][j][3]=0.f; }

  #pragma unroll
  for (int ks = 0; ks < 3; ++ks){
    short8 a[6];
    #pragma unroll
    for (int mt = 0; mt < 6; ++mt)
      a[mt] = *(const short8*)(aw + (mt * 16 + l15) * 104 + ks * 32 + l4 * 8);
    #pragma unroll
    for (int nt = 0; nt < 4; ++nt){
      const short8 bv = *(const short8*)(xT + (w * 64 + nt * 16 + l15) * 104 + ks * 32 + l4 * 8);
      #pragma unroll
      for (int mt = 0; mt < 6; ++mt)
        acc[mt][nt] = __builtin_amdgcn_mfma_f32_16x16x32_bf16(a[mt], bv, acc[mt][nt], 0, 0, 0);
    }
  }

  float* D = Dst + (size_t)b * C_ * HW_ + p0;
  #pragma unroll
  for (int mt = 0; mt < 6; ++mt)
    #pragma unroll
    for (int nt = 0; nt < 4; ++nt)
      #pragma unroll
      for (int r = 0; r < 4; ++r)
        D[(size_t)(mt * 16 + l4 * 4 + r) * HW_ + w * 64 + nt * 16 + l15] = acc[mt][nt][r];
}

// ---------------- k_gram: G[b,h] = q_bh @ k_bh^T ----------------
__global__ __launch_bounds__(256, 2)
void k_gram(const unsigned short* __restrict__ qb, const unsigned short* __restrict__ kb,
            float* __restrict__ Gp)
{
  __shared__ unsigned short pan[2][32 * 520];   // 66,560 B
  const int t = threadIdx.x, lane = t & 63, w = t >> 6;
  const int ns = blockIdx.x, bh = blockIdx.y;
  const int b = bh / 3, h = bh - b * 3;
  const size_t base = ((size_t)b * C_ + h * 32) * HW_ + ns * 1536;
  const int l31 = lane & 31, l5 = lane >> 5;

  f32x16 acc;
  #pragma unroll
  for (int r = 0; r < 16; ++r) acc[r] = 0.f;

  #pragma unroll 1
  for (int rd = 0; rd < 3; ++rd){
    __syncthreads();
    #pragma unroll 8
    for (int j = 0; j < 64; ++j){
      const int idx = j * 256 + t;
      const int op = idx >> 13;
      const int rem = idx & 8191;
      const int ch = rem >> 8, dcol = rem & 255;
      const unsigned* src = (const unsigned*)((op ? kb : qb) + base + (size_t)ch * HW_ + rd * 512) + dcol;
      *(unsigned*)(&pan[op][ch * 520 + dcol * 2]) = *src;
    }
    __syncthreads();
    #pragma unroll
    for (int j8 = 0; j8 < 8; ++j8){
      const int s = j8 * 4 + w;
      const short8 av = *(const short8*)(&pan[0][l31 * 520 + s * 16 + l5 * 8]);
      const short8 bv = *(const short8*)(&pan[1][l31 * 520 + s * 16 + l5 * 8]);
      acc = __builtin_amdgcn_mfma_f32_32x32x16_bf16(av, bv, acc, 0, 0, 0);
    }
  }
  __syncthreads();
  float* red = (float*)pan;
  #pragma unroll
  for (int r = 0; r < 16; ++r) red[w * 1024 + r * 64 + lane] = acc[r];
  __syncthreads();
  #pragma unroll
  for (int q = 0; q < 4; ++q){
    const int fi = q * 256 + t;
    const float v = red[fi] + red[1024 + fi] + red[2048 + fi] + red[3072 + fi];
    const int rr = fi >> 6, ll = fi & 63;
    const int c = (rr & 3) + 8 * (rr >> 2) + 4 * (ll >> 5);   // m101 C-layout
    const int d = ll & 31;
    Gp[(((size_t)ns * 24 + bh) * 32 + c) * 32 + d] = v;
  }
}

// ---------------- k_attn: norms + softmax + M = proj @ attn_bd ----------------
__global__ __launch_bounds__(256)
void k_attn(const float* __restrict__ Gp, const float* __restrict__ qqp,
            const float* __restrict__ kkp, const float* __restrict__ temp,
            const float* __restrict__ proj, float* __restrict__ M)
{
  const int b = blockIdx.x, t = threadIdx.x;
  __shared__ float at[3][32][32];
  __shared__ float ninv[2][C_];
  if (t < 2 * C_){
    const int kind = t / C_, r = t - kind * C_;
    const float* P = kind ? kkp : qqp;
    float s = 0.f;
    #pragma unroll
    for (int ns = 0; ns < NB_; ++ns) s += P[((size_t)b * NB_ + ns) * C_ + r];
    ninv[kind][r] = 1.f / fmaxf(sqrtf(s), 1e-12f);
  }
  __syncthreads();
  for (int idx = t; idx < 3 * 1024; idx += 256){
    const int h = idx >> 10, rem = idx & 1023, cc = rem >> 5, dd = rem & 31;
    float g = 0.f;
    #pragma unroll
    for (int ns = 0; ns < 24; ++ns)
      g += Gp[(((size_t)ns * 24 + b * 3 + h) * 32 + cc) * 32 + dd];
    at[h][cc][dd] = g * ninv[0][h * 32 + cc] * ninv[1][h * 32 + dd] * temp[h];
  }
  __syncthreads();
  if (t < C_){
    const int h = t >> 5, cc = t & 31;
    float m = -1e30f;
    for (int dd = 0; dd < 32; ++dd) m = fmaxf(m, at[h][cc][dd]);
    float s = 0.f;
    for (int dd = 0; dd < 32; ++dd){ const float e = expf(at[h][cc][dd] - m); at[h][cc][dd] = e; s += e; }
    const float inv = 1.f / s;
    for (int dd = 0; dd < 32; ++dd) at[h][cc][dd] *= inv;
  }
  __syncthreads();
  for (int idx = t; idx < C_ * C_; idx += 256){
    const int o = idx / 96, hd = idx - o * 96, h = hd >> 5, dd = hd & 31;
    float m = 0.f;
    #pragma unroll
    for (int cc = 0; cc < 32; ++cc)
      m = fmaf(proj[o * 96 + h * 32 + cc], at[h][cc][dd], m);
    M[(size_t)b * 9216 + idx] = m;
  }
}

extern "C" void kernel_launch(void* const* d_in, const int* in_sizes, int n_in,
                              void* d_out, int out_size, void* d_ws, size_t ws_size,
                              hipStream_t stream)
{
  const float* x     = (const float*)d_in[0];
  const float* y     = (const float*)d_in[1];
  const float* z     = (const float*)d_in[2];
  const float* temp  = (const float*)d_in[3];
  const float* q_pwc = (const float*)d_in[4];
  const float* q_dwc = (const float*)d_in[5];
  const float* k_pwc = (const float*)d_in[6];
  const float* k_dwc = (const float*)d_in[7];
  const float* v_pwc = (const float*)d_in[8];
  const float* v_dwc = (const float*)d_in[9];
  const float* proj  = (const float*)d_in[10];

  // workspace layout
  char* ws = (char*)d_ws;
  unsigned short* qb = (unsigned short*)(ws + 56623104);
  unsigned short* kb = (unsigned short*)(ws + 113246208);
  unsigned short* vb = (unsigned short*)(ws + 169869312);      // end 226,492,416
  float* qqp = (float*)(ws + 226492416);                       // 98,304
  float* kkp = (float*)(ws + 226590720);                       // 98,304
  float* Gp  = (float*)(ws + 4194304);                         // 589,824 (free region)
  float* M   = (float*)(ws + 8388608);                         // 294,912 (free region)
  float* out = (float*)d_out;

  k_conv_all<<<dim3(NB_, B_, 3), 768, 0, stream>>>(
      x, y, z, q_pwc, k_pwc, v_pwc, q_dwc, k_dwc, v_dwc, qb, kb, vb, qqp, kkp);
  k_gram<<<dim3(24, 24), 256, 0, stream>>>(qb, kb, Gp);
  k_attn<<<B_, 256, 0, stream>>>(Gp, qqp, kkp, temp, proj, M);
  k_gemm<<<dim3(HW_ / 256, B_), 256, 0, stream>>>(vb, M, out);
}

// Round 16
// 420.750 us; speedup vs baseline: 1.0018x; 1.0018x over previous
//
#include <hip/hip_runtime.h>

// CrossAttention MI355X — round 16 (= round-15 + amdgpu_waves_per_eu(3,3) on
// k_conv_all). r15's rotation state spilled to scratch (WRITE 550MB vs 170MB
// output; VGPR=84): the allocator targeted 6 waves/EU it can never get (LDS
// caps at 12 waves/CU = 3/EU). Pinning waves-per-EU to exactly 3 raises the
// VGPR budget to 170 and should eliminate the spill.
//  k_conv_all      : q/k/v = in + dw3x3(pw @ in)
//  k_gram          : G[b,h] = q @ k^T    (32x32x16 MFMA)
//  k_attn          : norms + softmax + M[b] = proj @ attn_blockdiag
//  k_gemm          : out = M[b] @ v      (f32 direct epilogue)

#define B_  8
#define C_  96
#define W_  192
#define HW_ 36864
#define NB_ 32     // row-bands per image (6 rows each)

typedef __attribute__((ext_vector_type(8)))  short short8;
typedef __attribute__((ext_vector_type(4)))  float f32x4;
typedef __attribute__((ext_vector_type(16))) float f32x16;

__device__ __forceinline__ unsigned short f2b(float f){
  unsigned u = __float_as_uint(f);
  u += 0x7fffu + ((u >> 16) & 1u);
  return (unsigned short)(u >> 16);
}
__device__ __forceinline__ float blo(unsigned u){ return __uint_as_float(u << 16); }
__device__ __forceinline__ float bhi(unsigned u){ return __uint_as_float(u & 0xffff0000u); }

// Barrier waiting only on LDS ops (lgkmcnt), not global stores (vmcnt).
__device__ __forceinline__ void barrier_lds(){
  asm volatile("s_waitcnt lgkmcnt(0)\n\ts_barrier" ::: "memory");
}

// ---------------- k_conv_all: out = in + dw3x3(pw @ in) ----------------------
// grid (32 bands, 8 b, 3 conv), block 768 (12 waves), 155.1KB LDS (1 blk/CU).
// Phase P(r), r = r0-1 .. r0+7, ONE barrier each:
//   issue stage-loads(r+1) -> GEMM(r): xrow[slr] -> hring[slr]  (or zero slot)
//   -> stage-write(r+1) into xrow[slr^1] -> read h row r-1 from hring[slr^1]
//   -> dwise(r-2) from reg rows (r-3, r-2) + new row (r-1) -> rotate.
__global__ __launch_bounds__(768)
__attribute__((amdgpu_waves_per_eu(3, 3)))
void k_conv_all(const float* __restrict__ x0, const float* __restrict__ x1,
                const float* __restrict__ x2,
                const float* __restrict__ pw0, const float* __restrict__ pw1,
                const float* __restrict__ pw2,
                const float* __restrict__ dw0, const float* __restrict__ dw1,
                const float* __restrict__ dw2,
                unsigned short* __restrict__ o0, unsigned short* __restrict__ o1,
                unsigned short* __restrict__ o2,
                float* __restrict__ n0, float* __restrict__ n1)
{
  __shared__ unsigned short xrow[2][192 * 104];   // 79,872 B [buf][pix][ch]
  __shared__ unsigned short hring[2][96 * 196];   // 75,264 B [slot][ch][1+col]

  const int t = threadIdx.x, lane = t & 63, wv = t >> 6;
  const int band = blockIdx.x, b = blockIdx.y, cid = blockIdx.z;
  const float* xsrc = (cid == 0) ? x0 : (cid == 1) ? x1 : x2;
  const float* pw   = (cid == 0) ? pw0 : (cid == 1) ? pw1 : pw2;
  const float* dwt  = (cid == 0) ? dw0 : (cid == 1) ? dw1 : dw2;
  unsigned short* outq = (cid == 0) ? o0 : (cid == 1) ? o1 : o2;
  float* nrm = (cid == 0) ? n0 : (cid == 1) ? n1 : nullptr;

  const int r0 = band * 6;
  const int l15 = lane & 15, l4 = lane >> 4;
  const int mtg = wv % 6, ntg = wv / 6;           // ntg 0..1
  const float* xb = xsrc + (size_t)b * C_ * HW_;

  // staging task decomposition: 2304 = 768 x 3 exactly (48cp x 48pg)
  int scp[3], spg[3];
  #pragma unroll
  for (int i = 0; i < 3; ++i){
    const int idx = i * 768 + t;
    scp[i] = idx / 48; spg[i] = idx - scp[i] * 48;
  }

  // pw A-frags in registers: single m-tile (16 rows) x 3 k-steps
  short8 afrag[3];
  #pragma unroll
  for (int ks = 0; ks < 3; ++ks){
    const int m = mtg * 16 + l15;
    const float* ap = pw + m * 96 + ks * 32 + l4 * 8;
    const float4 f0 = *(const float4*)ap;
    const float4 f1 = *(const float4*)(ap + 4);
    union { short8 v; unsigned short u[8]; } tmp;
    tmp.u[0]=f2b(f0.x); tmp.u[1]=f2b(f0.y); tmp.u[2]=f2b(f0.z); tmp.u[3]=f2b(f0.w);
    tmp.u[4]=f2b(f1.x); tmp.u[5]=f2b(f1.y); tmp.u[6]=f2b(f1.z); tmp.u[7]=f2b(f1.w);
    afrag[ks] = tmp.v;
  }

  // zero BOTH ring slots once: halo cols (idx 0, 193..195) must start zero —
  // the GEMM only ever writes idx 1..192.  4704 uint4 = 75,264 B.
  {
    uint4* p = (uint4*)&hring[0][0];
    for (int i = t; i < 4704; i += 768) p[i] = make_uint4(0,0,0,0);
  }

  float ssq[8];
  #pragma unroll
  for (int i = 0; i < 8; ++i) ssq[i] = 0.f;

  // rotation state: packed h rows (uint2.x, uint2.y, ext dword) per channel
  unsigned h0lo[8], h0hi[8], h0ex[8];   // row r-3 at dwise time
  unsigned h1lo[8], h1hi[8], h1ex[8];   // row r-2

  auto stage_load = [&](int rs, float4* fa, float4* fb){
    #pragma unroll
    for (int i = 0; i < 3; ++i){
      const float* xp = xb + (size_t)(2*scp[i]) * HW_ + (size_t)rs * W_ + 4*spg[i];
      fa[i] = *(const float4*)xp;
      fb[i] = *(const float4*)(xp + HW_);
    }
  };
  auto stage_write = [&](int buf, const float4* fa, const float4* fb){
    unsigned short* xw = &xrow[buf][0];
    #pragma unroll
    for (int i = 0; i < 3; ++i){
      const int pg = spg[i];
      const unsigned pk0 = (unsigned)f2b(fa[i].x) | ((unsigned)f2b(fb[i].x) << 16);
      const unsigned pk1 = (unsigned)f2b(fa[i].y) | ((unsigned)f2b(fb[i].y) << 16);
      const unsigned pk2 = (unsigned)f2b(fa[i].z) | ((unsigned)f2b(fb[i].z) << 16);
      const unsigned pk3 = (unsigned)f2b(fa[i].w) | ((unsigned)f2b(fb[i].w) << 16);
      const int s = (pg >> 1) & 3;                 // XOR-barrel bank spread
      const unsigned a0 = (s & 1) ? pk1 : pk0;
      const unsigned a1 = (s & 1) ? pk0 : pk1;
      const unsigned a2 = (s & 1) ? pk3 : pk2;
      const unsigned a3 = (s & 1) ? pk2 : pk3;
      const unsigned q0 = (s & 2) ? a2 : a0;
      const unsigned q1 = (s & 2) ? a3 : a1;
      const unsigned q2 = (s & 2) ? a0 : a2;
      const unsigned q3 = (s & 2) ? a1 : a3;
      unsigned short* basep = xw + (4*pg) * 104 + 2*scp[i];
      *(unsigned*)(basep + ((0 ^ s) * 104)) = q0;
      *(unsigned*)(basep + ((1 ^ s) * 104)) = q1;
      *(unsigned*)(basep + ((2 ^ s) * 104)) = q2;
      *(unsigned*)(basep + ((3 ^ s) * 104)) = q3;
    }
  };

  // prologue: stage row r0-1 into xrow[(r0+3)&1] if in image
  if (r0 - 1 >= 0){
    float4 fa[3], fb[3];
    stage_load(r0 - 1, fa, fb);
    stage_write((r0 + 3) & 1, fa, fb);
  }
  barrier_lds();

  #pragma unroll 1
  for (int r = r0 - 1; r <= r0 + 7; ++r){
    const int slr = (r + 4) & 1;           // xrow buf and ring slot for row r
    const int rs = r + 1;
    const bool do_stage = (rs <= r0 + 6) && (rs < 192);
    float4 sfa[3], sfb[3];
    if (do_stage) stage_load(rs, sfa, sfb);   // issue early

    // ---- GEMM row r (or zero slot)
    if (r <= r0 + 6){
      if (r >= 0 && r < 192){
        const unsigned short* xr = &xrow[slr][0];
        f32x4 acc[6];
        #pragma unroll
        for (int nt = 0; nt < 6; ++nt){
          acc[nt][0]=0.f; acc[nt][1]=0.f; acc[nt][2]=0.f; acc[nt][3]=0.f;
        }
        #pragma unroll
        for (int ks = 0; ks < 3; ++ks){
          #pragma unroll
          for (int nt = 0; nt < 6; ++nt){
            const short8 bv = *(const short8*)(xr + (ntg*96 + nt*16 + l15) * 104 + ks*32 + l4*8);
            acc[nt] = __builtin_amdgcn_mfma_f32_16x16x32_bf16(afrag[ks], bv, acc[nt], 0, 0, 0);
          }
        }
        unsigned short* hs = &hring[slr][0];
        #pragma unroll
        for (int nt = 0; nt < 6; ++nt)
          #pragma unroll
          for (int reg = 0; reg < 4; ++reg){
            const int m = mtg*16 + l4*4 + reg;            // out-ch
            const int n = ntg*96 + nt*16 + l15;           // pix col
            hs[m * 196 + 1 + n] = f2b(acc[nt][reg]);
          }
      } else {
        uint4* p = (uint4*)&hring[slr][0];
        for (int i = t; i < 2352; i += 768) p[i] = make_uint4(0,0,0,0);
      }
    }

    // ---- stage-write(r+1) (frees stage regs before dwise)
    if (do_stage) stage_write(slr ^ 1, sfa, sfb);

    // ---- read newest h row (r-1) + dwise(r-2) + rotate
    if (r >= r0){
      unsigned nlo[8], nhi[8], nex[8];
      if (lane < 48){
        const int g = lane;
        const unsigned short* hb_ = &hring[slr ^ 1][0];   // row r-1
        #pragma unroll
        for (int cc = 0; cc < 8; ++cc){
          const unsigned short* hp = hb_ + (wv*8 + cc) * 196 + 4*g;
          const uint2 ua = *(const uint2*)hp;             // imgcols 4g-1..4g+2
          nlo[cc] = ua.x; nhi[cc] = ua.y;
          nex[cc] = *(const unsigned*)(hp + 4);           // imgcols 4g+3,4g+4
        }
        if (r >= r0 + 2){
          const int rr = r - 2;                           // output row
          float4 xr_[8];                                  // hoisted residual
          const float* xrp = xb + (size_t)rr * W_ + 4*g;
          #pragma unroll
          for (int cc = 0; cc < 8; ++cc)
            xr_[cc] = *(const float4*)(xrp + (size_t)(wv*8 + cc) * HW_);
          #pragma unroll
          for (int cc = 0; cc < 8; ++cc){
            const int chs = __builtin_amdgcn_readfirstlane(wv*8 + cc);
            float wgt[9];
            #pragma unroll
            for (int i = 0; i < 9; ++i) wgt[i] = dwt[chs * 9 + i];   // s_load
            float hv[3][6];
            hv[0][0]=blo(h0lo[cc]); hv[0][1]=bhi(h0lo[cc]); hv[0][2]=blo(h0hi[cc]);
            hv[0][3]=bhi(h0hi[cc]); hv[0][4]=blo(h0ex[cc]); hv[0][5]=bhi(h0ex[cc]);
            hv[1][0]=blo(h1lo[cc]); hv[1][1]=bhi(h1lo[cc]); hv[1][2]=blo(h1hi[cc]);
            hv[1][3]=bhi(h1hi[cc]); hv[1][4]=blo(h1ex[cc]); hv[1][5]=bhi(h1ex[cc]);
            hv[2][0]=blo(nlo[cc]);  hv[2][1]=bhi(nlo[cc]);  hv[2][2]=blo(nhi[cc]);
            hv[2][3]=bhi(nhi[cc]);  hv[2][4]=blo(nex[cc]);  hv[2][5]=bhi(nex[cc]);
            float o[4] = {xr_[cc].x, xr_[cc].y, xr_[cc].z, xr_[cc].w};
            #pragma unroll
            for (int j = 0; j < 4; ++j){
              float s = o[j];
              #pragma unroll
              for (int d = 0; d < 3; ++d){
                s = fmaf(wgt[d*3+0], hv[d][j],   s);
                s = fmaf(wgt[d*3+1], hv[d][j+1], s);
                s = fmaf(wgt[d*3+2], hv[d][j+2], s);
              }
              o[j] = s;
              ssq[cc] = fmaf(s, s, ssq[cc]);
            }
            const size_t cb = (size_t)(b * C_ + chs) * HW_ + (size_t)rr * W_ + 4*g;
            const unsigned p0 = (unsigned)f2b(o[0]) | ((unsigned)f2b(o[1]) << 16);
            const unsigned p1 = (unsigned)f2b(o[2]) | ((unsigned)f2b(o[3]) << 16);
            *(uint2*)(outq + cb) = make_uint2(p0, p1);
          }
        }
        #pragma unroll
        for (int cc = 0; cc < 8; ++cc){                   // rotate
          h0lo[cc]=h1lo[cc]; h0hi[cc]=h1hi[cc]; h0ex[cc]=h1ex[cc];
          h1lo[cc]=nlo[cc];  h1hi[cc]=nhi[cc];  h1ex[cc]=nex[cc];
        }
      }
    }
    barrier_lds();
  }

  if (nrm){
    #pragma unroll
    for (int cc = 0; cc < 8; ++cc){
      float s = ssq[cc];                     // lanes 48..63 contribute 0
      #pragma unroll
      for (int off = 32; off; off >>= 1) s += __shfl_xor(s, off);
      if (lane == 0)
        nrm[((size_t)b * NB_ + band) * C_ + wv * 8 + cc] = s;
    }
  }
}

// ---------------- k_gemm: out[96][36864] = M(96x96,per-b) @ v ----------------
__global__ __launch_bounds__(256, 2)
void k_gemm(const unsigned short* __restrict__ Bsrc, const float* __restrict__ Asrc,
            float* __restrict__ Dst)
{
  __shared__ unsigned short xT[256 * 104];   // 53,248 B  [pix][ch]
  __shared__ unsigned short aw[96 * 104];    // 19,968 B  [m][k]
  const int t = threadIdx.x;
  const int b = blockIdx.y;
  const int p0 = blockIdx.x * 256;
  const int lane = t & 63, w = t >> 6;
  const int l15 = lane & 15, l4 = lane >> 4;

  const float* Ab = Asrc + b * C_ * C_;
  #pragma unroll
  for (int j = 0; j < 18; ++j){
    const int pi = j * 256 + t;
    const int row = pi / 48, c2 = (pi - row * 48) * 2;
    const float a0 = Ab[row * 96 + c2], a1 = Ab[row * 96 + c2 + 1];
    *(unsigned*)(aw + row * 104 + c2) = (unsigned)f2b(a0) | ((unsigned)f2b(a1) << 16);
  }
  #pragma unroll 1
  for (int i = 0; i < 12; ++i){
    const int idx = i * 256 + t;
    const int cp = idx >> 6, pg = idx & 63;
    const unsigned short* vp = Bsrc + (size_t)b * C_ * HW_ + (size_t)(2*cp) * HW_ + p0 + 4*pg;
    const uint2 ua = *(const uint2*)vp;          // 4 px of ch 2cp
    const uint2 ub = *(const uint2*)(vp + HW_);  // 4 px of ch 2cp+1
    const unsigned pk0 = (ua.x & 0xffffu) | (ub.x << 16);
    const unsigned pk1 = (ua.x >> 16)     | (ub.x & 0xffff0000u);
    const unsigned pk2 = (ua.y & 0xffffu) | (ub.y << 16);
    const unsigned pk3 = (ua.y >> 16)     | (ub.y & 0xffff0000u);
    const int s = (pg >> 1) & 3;
    const unsigned a0 = (s & 1) ? pk1 : pk0;
    const unsigned a1 = (s & 1) ? pk0 : pk1;
    const unsigned a2 = (s & 1) ? pk3 : pk2;
    const unsigned a3 = (s & 1) ? pk2 : pk3;
    const unsigned q0 = (s & 2) ? a2 : a0;
    const unsigned q1 = (s & 2) ? a3 : a1;
    const unsigned q2 = (s & 2) ? a0 : a2;
    const unsigned q3 = (s & 2) ? a1 : a3;
    unsigned short* basep = xT + (4*pg) * 104 + 2*cp;
    *(unsigned*)(basep + ((0 ^ s) * 104)) = q0;
    *(unsigned*)(basep + ((1 ^ s) * 104)) = q1;
    *(unsigned*)(basep + ((2 ^ s) * 104)) = q2;
    *(unsigned*)(basep + ((3 ^ s) * 104)) = q3;
  }
  __syncthreads();

  f32x4 acc[6][4];
  #pragma unroll
  for (int i = 0; i < 6; ++i)
    #pragma unroll
    for (int j = 0; j < 4; ++j){ acc[i][j][0]=0.f; acc[i][j][1]=0.f; acc[i][j][2]=0.f; acc[i][j][3]=0.f; }

  #pragma unroll
  for (int ks = 0; ks < 3; ++ks){
    short8 a[6];
    #pragma unroll
    for (int mt = 0; mt < 6; ++mt)
      a[mt] = *(const short8*)(aw + (mt * 16 + l15) * 104 + ks * 32 + l4 * 8);
    #pragma unroll
    for (int nt = 0; nt < 4; ++nt){
      const short8 bv = *(const short8*)(xT + (w * 64 + nt * 16 + l15) * 104 + ks * 32 + l4 * 8);
      #pragma unroll
      for (int mt = 0; mt < 6; ++mt)
        acc[mt][nt] = __builtin_amdgcn_mfma_f32_16x16x32_bf16(a[mt], bv, acc[mt][nt], 0, 0, 0);
    }
  }

  float* D = Dst + (size_t)b * C_ * HW_ + p0;
  #pragma unroll
  for (int mt = 0; mt < 6; ++mt)
    #pragma unroll
    for (int nt = 0; nt < 4; ++nt)
      #pragma unroll
      for (int r = 0; r < 4; ++r)
        D[(size_t)(mt * 16 + l4 * 4 + r) * HW_ + w * 64 + nt * 16 + l15] = acc[mt][nt][r];
}

// ---------------- k_gram: G[b,h] = q_bh @ k_bh^T ----------------
__global__ __launch_bounds__(256, 2)
void k_gram(const unsigned short* __restrict__ qb, const unsigned short* __restrict__ kb,
            float* __restrict__ Gp)
{
  __shared__ unsigned short pan[2][32 * 520];   // 66,560 B
  const int t = threadIdx.x, lane = t & 63, w = t >> 6;
  const int ns = blockIdx.x, bh = blockIdx.y;
  const int b = bh / 3, h = bh - b * 3;
  const size_t base = ((size_t)b * C_ + h * 32) * HW_ + ns * 1536;
  const int l31 = lane & 31, l5 = lane >> 5;

  f32x16 acc;
  #pragma unroll
  for (int r = 0; r < 16; ++r) acc[r] = 0.f;

  #pragma unroll 1
  for (int rd = 0; rd < 3; ++rd){
    __syncthreads();
    #pragma unroll 8
    for (int j = 0; j < 64; ++j){
      const int idx = j * 256 + t;
      const int op = idx >> 13;
      const int rem = idx & 8191;
      const int ch = rem >> 8, dcol = rem & 255;
      const unsigned* src = (const unsigned*)((op ? kb : qb) + base + (size_t)ch * HW_ + rd * 512) + dcol;
      *(unsigned*)(&pan[op][ch * 520 + dcol * 2]) = *src;
    }
    __syncthreads();
    #pragma unroll
    for (int j8 = 0; j8 < 8; ++j8){
      const int s = j8 * 4 + w;
      const short8 av = *(const short8*)(&pan[0][l31 * 520 + s * 16 + l5 * 8]);
      const short8 bv = *(const short8*)(&pan[1][l31 * 520 + s * 16 + l5 * 8]);
      acc = __builtin_amdgcn_mfma_f32_32x32x16_bf16(av, bv, acc, 0, 0, 0);
    }
  }
  __syncthreads();
  float* red = (float*)pan;
  #pragma unroll
  for (int r = 0; r < 16; ++r) red[w * 1024 + r * 64 + lane] = acc[r];
  __syncthreads();
  #pragma unroll
  for (int q = 0; q < 4; ++q){
    const int fi = q * 256 + t;
    const float v = red[fi] + red[1024 + fi] + red[2048 + fi] + red[3072 + fi];
    const int rr = fi >> 6, ll = fi & 63;
    const int c = (rr & 3) + 8 * (rr >> 2) + 4 * (ll >> 5);   // m101 C-layout
    const int d = ll & 31;
    Gp[(((size_t)ns * 24 + bh) * 32 + c) * 32 + d] = v;
  }
}

// ---------------- k_attn: norms + softmax + M = proj @ attn_bd ----------------
__global__ __launch_bounds__(256)
void k_attn(const float* __restrict__ Gp, const float* __restrict__ qqp,
            const float* __restrict__ kkp, const float* __restrict__ temp,
            const float* __restrict__ proj, float* __restrict__ M)
{
  const int b = blockIdx.x, t = threadIdx.x;
  __shared__ float at[3][32][32];
  __shared__ float ninv[2][C_];
  if (t < 2 * C_){
    const int kind = t / C_, r = t - kind * C_;
    const float* P = kind ? kkp : qqp;
    float s = 0.f;
    #pragma unroll
    for (int ns = 0; ns < NB_; ++ns) s += P[((size_t)b * NB_ + ns) * C_ + r];
    ninv[kind][r] = 1.f / fmaxf(sqrtf(s), 1e-12f);
  }
  __syncthreads();
  for (int idx = t; idx < 3 * 1024; idx += 256){
    const int h = idx >> 10, rem = idx & 1023, cc = rem >> 5, dd = rem & 31;
    float g = 0.f;
    #pragma unroll
    for (int ns = 0; ns < 24; ++ns)
      g += Gp[(((size_t)ns * 24 + b * 3 + h) * 32 + cc) * 32 + dd];
    at[h][cc][dd] = g * ninv[0][h * 32 + cc] * ninv[1][h * 32 + dd] * temp[h];
  }
  __syncthreads();
  if (t < C_){
    const int h = t >> 5, cc = t & 31;
    float m = -1e30f;
    for (int dd = 0; dd < 32; ++dd) m = fmaxf(m, at[h][cc][dd]);
    float s = 0.f;
    for (int dd = 0; dd < 32; ++dd){ const float e = expf(at[h][cc][dd] - m); at[h][cc][dd] = e; s += e; }
    const float inv = 1.f / s;
    for (int dd = 0; dd < 32; ++dd) at[h][cc][dd] *= inv;
  }
  __syncthreads();
  for (int idx = t; idx < C_ * C_; idx += 256){
    const int o = idx / 96, hd = idx - o * 96, h = hd >> 5, dd = hd & 31;
    float m = 0.f;
    #pragma unroll
    for (int cc = 0; cc < 32; ++cc)
      m = fmaf(proj[o * 96 + h * 32 + cc], at[h][cc][dd], m);
    M[(size_t)b * 9216 + idx] = m;
  }
}

extern "C" void kernel_launch(void* const* d_in, const int* in_sizes, int n_in,
                              void* d_out, int out_size, void* d_ws, size_t ws_size,
                              hipStream_t stream)
{
  const float* x     = (const float*)d_in[0];
  const float* y     = (const float*)d_in[1];
  const float* z     = (const float*)d_in[2];
  const float* temp  = (const float*)d_in[3];
  const float* q_pwc = (const float*)d_in[4];
  const float* q_dwc = (const float*)d_in[5];
  const float* k_pwc = (const float*)d_in[6];
  const float* k_dwc = (const float*)d_in[7];
  const float* v_pwc = (const float*)d_in[8];
  const float* v_dwc = (const float*)d_in[9];
  const float* proj  = (const float*)d_in[10];

  // workspace layout
  char* ws = (char*)d_ws;
  unsigned short* qb = (unsigned short*)(ws + 56623104);
  unsigned short* kb = (unsigned short*)(ws + 113246208);
  unsigned short* vb = (unsigned short*)(ws + 169869312);      // end 226,492,416
  float* qqp = (float*)(ws + 226492416);                       // 98,304
  float* kkp = (float*)(ws + 226590720);                       // 98,304
  float* Gp  = (float*)(ws + 4194304);                         // 589,824 (free region)
  float* M   = (float*)(ws + 8388608);                         // 294,912 (free region)
  float* out = (float*)d_out;

  k_conv_all<<<dim3(NB_, B_, 3), 768, 0, stream>>>(
      x, y, z, q_pwc, k_pwc, v_pwc, q_dwc, k_dwc, v_dwc, qb, kb, vb, qqp, kkp);
  k_gram<<<dim3(24, 24), 256, 0, stream>>>(qb, kb, Gp);
  k_attn<<<B_, 256, 0, stream>>>(Gp, qqp, kkp, temp, proj, M);
  k_gemm<<<dim3(HW_ / 256, B_), 256, 0, stream>>>(vb, M, out);
}

// Round 17
// 357.640 us; speedup vs baseline: 1.1786x; 1.1765x over previous
//
#include <hip/hip_runtime.h>

// CrossAttention MI355X — round 17: revert to the proven r13 structure
// (3-slot ring, no register rotation — r14-16's rotation arrays spilled to
// scratch regardless of VGPR budget) and raise k_conv_all to 1024 threads
// (16 waves = 4/SIMD, +33% latency hiding at the same 152.8KB LDS / 1 blk/CU).
//  k_conv_all      : q/k/v = in + dw3x3(pw @ in), h in 3-row LDS ring
//  k_gram          : G[b,h] = q @ k^T    (32x32x16 MFMA)
//  k_attn          : norms + softmax + M[b] = proj @ attn_blockdiag
//  k_gemm          : out = M[b] @ v      (f32 direct epilogue)

#define B_  8
#define C_  96
#define W_  192
#define HW_ 36864
#define NB_ 32     // row-bands per image (6 rows each)

typedef __attribute__((ext_vector_type(8)))  short short8;
typedef __attribute__((ext_vector_type(4)))  float f32x4;
typedef __attribute__((ext_vector_type(16))) float f32x16;

__device__ __forceinline__ unsigned short f2b(float f){
  unsigned u = __float_as_uint(f);
  u += 0x7fffu + ((u >> 16) & 1u);
  return (unsigned short)(u >> 16);
}
__device__ __forceinline__ float blo(unsigned u){ return __uint_as_float(u << 16); }
__device__ __forceinline__ float bhi(unsigned u){ return __uint_as_float(u & 0xffff0000u); }

// Barrier waiting only on LDS ops (lgkmcnt), not global stores (vmcnt).
// All global->consumer deps here are same-thread register deps.
__device__ __forceinline__ void barrier_lds(){
  asm volatile("s_waitcnt lgkmcnt(0)\n\ts_barrier" ::: "memory");
}

// ---------------- k_conv_all: out = in + dw3x3(pw @ in), h in LDS ring -------
// grid (32 bands, 8 b, 3 conv), block 1024 (16 waves), 152.8KB LDS (1 blk/CU).
// GEMM: waves 0..11 = (mtg=w%6, ntg=w/6) -> 16x96 tile (18 MFMA each); waves
// 12..15 idle in phase A (GEMM crit path unchanged; they add latency hiding in
// the memory phases). Dwise: wave owns 6 channels, lanes 0..47 = 4-col groups.
// Per row r: phase A = issue stage-loads(r+1) to regs, row-GEMM -> ring slot;
// phase B = reg->LDS stage-write(r+1) ∥ dwise(r-1).
__global__ __launch_bounds__(1024, 1)
void k_conv_all(const float* __restrict__ x0, const float* __restrict__ x1,
                const float* __restrict__ x2,
                const float* __restrict__ pw0, const float* __restrict__ pw1,
                const float* __restrict__ pw2,
                const float* __restrict__ dw0, const float* __restrict__ dw1,
                const float* __restrict__ dw2,
                unsigned short* __restrict__ o0, unsigned short* __restrict__ o1,
                unsigned short* __restrict__ o2,
                float* __restrict__ n0, float* __restrict__ n1)
{
  __shared__ unsigned short xrow[192 * 104];      // 39,936 B  [pix][ch]
  __shared__ unsigned short hring[3][96 * 196];   // 112,896 B [slot][ch][1+col]

  const int t = threadIdx.x, lane = t & 63, wv = t >> 6;   // wv 0..15
  const int band = blockIdx.x, b = blockIdx.y, cid = blockIdx.z;
  const float* xsrc = (cid == 0) ? x0 : (cid == 1) ? x1 : x2;
  const float* pw   = (cid == 0) ? pw0 : (cid == 1) ? pw1 : pw2;
  const float* dwt  = (cid == 0) ? dw0 : (cid == 1) ? dw1 : dw2;
  unsigned short* outq = (cid == 0) ? o0 : (cid == 1) ? o1 : o2;
  float* nrm = (cid == 0) ? n0 : (cid == 1) ? n1 : nullptr;

  const int r0 = band * 6;
  const int l15 = lane & 15, l4 = lane >> 4;
  const int mtg = wv % 6, ntg = wv / 6;           // GEMM mapping valid for wv<12
  const float* xb = xsrc + (size_t)b * C_ * HW_;

  // staging task decomposition: 2304 tasks (48cp x 48pg) over 1024 threads
  int scp[3], spg[3];
  #pragma unroll
  for (int i = 0; i < 3; ++i){
    const int idx = i * 1024 + t;
    scp[i] = idx / 48; spg[i] = idx - scp[i] * 48;   // valid iff scp[i] < 48
  }

  // pw A-frags in registers: single m-tile (16 rows) x 3 k-steps
  short8 afrag[3];
  #pragma unroll
  for (int ks = 0; ks < 3; ++ks){
    const int m = mtg * 16 + l15;
    const float* ap = pw + m * 96 + ks * 32 + l4 * 8;
    const float4 f0 = *(const float4*)ap;
    const float4 f1 = *(const float4*)(ap + 4);
    union { short8 v; unsigned short u[8]; } tmp;
    tmp.u[0]=f2b(f0.x); tmp.u[1]=f2b(f0.y); tmp.u[2]=f2b(f0.z); tmp.u[3]=f2b(f0.w);
    tmp.u[4]=f2b(f1.x); tmp.u[5]=f2b(f1.y); tmp.u[6]=f2b(f1.z); tmp.u[7]=f2b(f1.w);
    afrag[ks] = tmp.v;
  }

  // zero ring once (covers halo cols 0 and 193..195 permanently)
  {
    uint4* p = (uint4*)&hring[0][0];
    for (int i = t; i < 7056; i += 1024) p[i] = make_uint4(0,0,0,0);
  }

  float ssq[6];
  #pragma unroll
  for (int i = 0; i < 6; ++i) ssq[i] = 0.f;

  auto stage_write = [&](const float4* fa, const float4* fb){
    #pragma unroll
    for (int i = 0; i < 3; ++i){
      if (scp[i] < 48){
        const int pg = spg[i];
        const unsigned pk0 = (unsigned)f2b(fa[i].x) | ((unsigned)f2b(fb[i].x) << 16);
        const unsigned pk1 = (unsigned)f2b(fa[i].y) | ((unsigned)f2b(fb[i].y) << 16);
        const unsigned pk2 = (unsigned)f2b(fa[i].z) | ((unsigned)f2b(fb[i].z) << 16);
        const unsigned pk3 = (unsigned)f2b(fa[i].w) | ((unsigned)f2b(fb[i].w) << 16);
        const int s = (pg >> 1) & 3;                 // XOR-barrel bank spread
        const unsigned a0 = (s & 1) ? pk1 : pk0;
        const unsigned a1 = (s & 1) ? pk0 : pk1;
        const unsigned a2 = (s & 1) ? pk3 : pk2;
        const unsigned a3 = (s & 1) ? pk2 : pk3;
        const unsigned q0 = (s & 2) ? a2 : a0;
        const unsigned q1 = (s & 2) ? a3 : a1;
        const unsigned q2 = (s & 2) ? a0 : a2;
        const unsigned q3 = (s & 2) ? a1 : a3;
        unsigned short* basep = xrow + (4*pg) * 104 + 2*scp[i];
        *(unsigned*)(basep + ((0 ^ s) * 104)) = q0;
        *(unsigned*)(basep + ((1 ^ s) * 104)) = q1;
        *(unsigned*)(basep + ((2 ^ s) * 104)) = q2;
        *(unsigned*)(basep + ((3 ^ s) * 104)) = q3;
      }
    }
  };
  auto stage_load = [&](int rs, float4* fa, float4* fb){
    #pragma unroll
    for (int i = 0; i < 3; ++i){
      if (scp[i] < 48){
        const float* xp = xb + (size_t)(2*scp[i]) * HW_ + (size_t)rs * W_ + 4*spg[i];
        fa[i] = *(const float4*)xp;
        fb[i] = *(const float4*)(xp + HW_);
      }
    }
  };

  // prologue: stage row r0-1 synchronously (if in image)
  if (r0 - 1 >= 0){
    float4 fa[3], fb[3];
    stage_load(r0 - 1, fa, fb);
    stage_write(fa, fb);
  }
  barrier_lds();

  #pragma unroll 1
  for (int r = r0 - 1; r <= r0 + 6; ++r){
    const int slot = (r + 3) % 3;
    const int rs = r + 1;
    const bool do_stage = (rs <= r0 + 6) && (rs < 192);   // rs >= 0 always here
    float4 sfa[3], sfb[3];
    if (do_stage) stage_load(rs, sfa, sfb);   // issue early; consumed in phase B

    // ---- phase A: row GEMM h[96][192] = pw @ xrow  (or zero slot)
    if (r >= 0 && r < 192){
      if (wv < 12){
        f32x4 acc[6];
        #pragma unroll
        for (int nt = 0; nt < 6; ++nt){
          acc[nt][0]=0.f; acc[nt][1]=0.f; acc[nt][2]=0.f; acc[nt][3]=0.f;
        }
        #pragma unroll
        for (int ks = 0; ks < 3; ++ks){
          #pragma unroll
          for (int nt = 0; nt < 6; ++nt){
            const short8 bv = *(const short8*)(xrow + (ntg*96 + nt*16 + l15) * 104 + ks*32 + l4*8);
            acc[nt] = __builtin_amdgcn_mfma_f32_16x16x32_bf16(afrag[ks], bv, acc[nt], 0, 0, 0);
          }
        }
        unsigned short* hs = &hring[slot][0];
        #pragma unroll
        for (int nt = 0; nt < 6; ++nt)
          #pragma unroll
          for (int reg = 0; reg < 4; ++reg){
            const int m = mtg*16 + l4*4 + reg;            // out-ch
            const int n = ntg*96 + nt*16 + l15;           // pix col
            hs[m * 196 + 1 + n] = f2b(acc[nt][reg]);
          }
      }
    } else {
      uint4* p = (uint4*)&hring[slot][0];
      for (int i = t; i < 2352; i += 1024) p[i] = make_uint4(0,0,0,0);
    }
    barrier_lds();   // ring row r ready; xrow free

    // ---- phase B: stage-write(r+1) ∥ dwise(r-1)
    if (do_stage) stage_write(sfa, sfb);
    if (r - 1 >= r0){
      const int rr = r - 1;
      const unsigned short* h0 = &hring[(rr + 2) % 3][0];   // row rr-1
      const unsigned short* h1 = &hring[(rr + 3) % 3][0];   // row rr
      const unsigned short* h2 = &hring[(rr + 4) % 3][0];   // row rr+1
      if (lane < 48){
        const int g = lane;
        float4 xr_[6];                       // hoisted residual prefetch
        const float* xrp = xb + (size_t)rr * W_ + 4*g;
        #pragma unroll
        for (int cc = 0; cc < 6; ++cc)
          xr_[cc] = *(const float4*)(xrp + (size_t)(wv * 6 + cc) * HW_);
        #pragma unroll
        for (int cc = 0; cc < 6; ++cc){
          const int chs = __builtin_amdgcn_readfirstlane(wv * 6 + cc);
          float wgt[9];
          #pragma unroll
          for (int i = 0; i < 9; ++i) wgt[i] = dwt[chs * 9 + i];   // s_load
          const int rb = chs * 196 + 4 * g;
          float hv[3][6];
          {
            const unsigned short* hp[3] = {h0 + rb, h1 + rb, h2 + rb};
            #pragma unroll
            for (int d = 0; d < 3; ++d){
              const uint2 ua = *(const uint2*)(hp[d]);           // imgcols 4g-1..4g+2
              const unsigned ub = *(const unsigned*)(hp[d] + 4); // imgcols 4g+3,4g+4
              hv[d][0]=blo(ua.x); hv[d][1]=bhi(ua.x); hv[d][2]=blo(ua.y);
              hv[d][3]=bhi(ua.y); hv[d][4]=blo(ub);   hv[d][5]=bhi(ub);
            }
          }
          float o[4] = {xr_[cc].x, xr_[cc].y, xr_[cc].z, xr_[cc].w};
          #pragma unroll
          for (int j = 0; j < 4; ++j){
            float s = o[j];
            #pragma unroll
            for (int d = 0; d < 3; ++d){
              s = fmaf(wgt[d*3+0], hv[d][j],   s);
              s = fmaf(wgt[d*3+1], hv[d][j+1], s);
              s = fmaf(wgt[d*3+2], hv[d][j+2], s);
            }
            o[j] = s;
            ssq[cc] = fmaf(s, s, ssq[cc]);
          }
          const size_t cb = (size_t)(b * C_ + chs) * HW_ + (size_t)rr * W_ + 4*g;
          const unsigned p0 = (unsigned)f2b(o[0]) | ((unsigned)f2b(o[1]) << 16);
          const unsigned p1 = (unsigned)f2b(o[2]) | ((unsigned)f2b(o[3]) << 16);
          *(uint2*)(outq + cb) = make_uint2(p0, p1);
        }
      }
    }
    barrier_lds();   // xrow(r+1) ready; ring slot (r+1)%3 free for overwrite
  }

  if (nrm){
    #pragma unroll
    for (int cc = 0; cc < 6; ++cc){
      float s = ssq[cc];                       // lanes 48..63 contribute 0
      #pragma unroll
      for (int off = 32; off; off >>= 1) s += __shfl_xor(s, off);
      if (lane == 0)
        nrm[((size_t)b * NB_ + band) * C_ + wv * 6 + cc] = s;
    }
  }
}

// ---------------- k_gemm: out[96][36864] = M(96x96,per-b) @ v ----------------
// grid (144, 8), block 256 (4 waves), 2 blocks/CU. v staged transposed
// [pix][104ch] via uint2 loads (4px) + pair-pack + XOR-barrel writes.
__global__ __launch_bounds__(256, 2)
void k_gemm(const unsigned short* __restrict__ Bsrc, const float* __restrict__ Asrc,
            float* __restrict__ Dst)
{
  __shared__ unsigned short xT[256 * 104];   // 53,248 B  [pix][ch]
  __shared__ unsigned short aw[96 * 104];    // 19,968 B  [m][k]
  const int t = threadIdx.x;
  const int b = blockIdx.y;
  const int p0 = blockIdx.x * 256;
  const int lane = t & 63, w = t >> 6;
  const int l15 = lane & 15, l4 = lane >> 4;

  const float* Ab = Asrc + b * C_ * C_;
  #pragma unroll
  for (int j = 0; j < 18; ++j){
    const int pi = j * 256 + t;
    const int row = pi / 48, c2 = (pi - row * 48) * 2;
    const float a0 = Ab[row * 96 + c2], a1 = Ab[row * 96 + c2 + 1];
    *(unsigned*)(aw + row * 104 + c2) = (unsigned)f2b(a0) | ((unsigned)f2b(a1) << 16);
  }
  #pragma unroll 1
  for (int i = 0; i < 12; ++i){
    const int idx = i * 256 + t;
    const int cp = idx >> 6, pg = idx & 63;
    const unsigned short* vp = Bsrc + (size_t)b * C_ * HW_ + (size_t)(2*cp) * HW_ + p0 + 4*pg;
    const uint2 ua = *(const uint2*)vp;          // 4 px of ch 2cp
    const uint2 ub = *(const uint2*)(vp + HW_);  // 4 px of ch 2cp+1
    const unsigned pk0 = (ua.x & 0xffffu) | (ub.x << 16);
    const unsigned pk1 = (ua.x >> 16)     | (ub.x & 0xffff0000u);
    const unsigned pk2 = (ua.y & 0xffffu) | (ub.y << 16);
    const unsigned pk3 = (ua.y >> 16)     | (ub.y & 0xffff0000u);
    const int s = (pg >> 1) & 3;
    const unsigned a0 = (s & 1) ? pk1 : pk0;
    const unsigned a1 = (s & 1) ? pk0 : pk1;
    const unsigned a2 = (s & 1) ? pk3 : pk2;
    const unsigned a3 = (s & 1) ? pk2 : pk3;
    const unsigned q0 = (s & 2) ? a2 : a0;
    const unsigned q1 = (s & 2) ? a3 : a1;
    const unsigned q2 = (s & 2) ? a0 : a2;
    const unsigned q3 = (s & 2) ? a1 : a3;
    unsigned short* basep = xT + (4*pg) * 104 + 2*cp;
    *(unsigned*)(basep + ((0 ^ s) * 104)) = q0;
    *(unsigned*)(basep + ((1 ^ s) * 104)) = q1;
    *(unsigned*)(basep + ((2 ^ s) * 104)) = q2;
    *(unsigned*)(basep + ((3 ^ s) * 104)) = q3;
  }
  __syncthreads();

  f32x4 acc[6][4];
  #pragma unroll
  for (int i = 0; i < 6; ++i)
    #pragma unroll
    for (int j = 0; j < 4; ++j){ acc[i][j][0]=0.f; acc[i][j][1]=0.f; acc[i][j][2]=0.f; acc[i][j][3]=0.f; }

  #pragma unroll
  for (int ks = 0; ks < 3; ++ks){
    short8 a[6];
    #pragma unroll
    for (int mt = 0; mt < 6; ++mt)
      a[mt] = *(const short8*)(aw + (mt * 16 + l15) * 104 + ks * 32 + l4 * 8);
    #pragma unroll
    for (int nt = 0; nt < 4; ++nt){
      const short8 bv = *(const short8*)(xT + (w * 64 + nt * 16 + l15) * 104 + ks * 32 + l4 * 8);
      #pragma unroll
      for (int mt = 0; mt < 6; ++mt)
        acc[mt][nt] = __builtin_amdgcn_mfma_f32_16x16x32_bf16(a[mt], bv, acc[mt][nt], 0, 0, 0);
    }
  }

  float* D = Dst + (size_t)b * C_ * HW_ + p0;
  #pragma unroll
  for (int mt = 0; mt < 6; ++mt)
    #pragma unroll
    for (int nt = 0; nt < 4; ++nt)
      #pragma unroll
      for (int r = 0; r < 4; ++r)
        D[(size_t)(mt * 16 + l4 * 4 + r) * HW_ + w * 64 + nt * 16 + l15] = acc[mt][nt][r];
}

// ---------------- k_gram: G[b,h] = q_bh @ k_bh^T ----------------
__global__ __launch_bounds__(256, 2)
void k_gram(const unsigned short* __restrict__ qb, const unsigned short* __restrict__ kb,
            float* __restrict__ Gp)
{
  __shared__ unsigned short pan[2][32 * 520];   // 66,560 B
  const int t = threadIdx.x, lane = t & 63, w = t >> 6;
  const int ns = blockIdx.x, bh = blockIdx.y;
  const int b = bh / 3, h = bh - b * 3;
  const size_t base = ((size_t)b * C_ + h * 32) * HW_ + ns * 1536;
  const int l31 = lane & 31, l5 = lane >> 5;

  f32x16 acc;
  #pragma unroll
  for (int r = 0; r < 16; ++r) acc[r] = 0.f;

  #pragma unroll 1
  for (int rd = 0; rd < 3; ++rd){
    __syncthreads();
    #pragma unroll 8
    for (int j = 0; j < 64; ++j){
      const int idx = j * 256 + t;
      const int op = idx >> 13;
      const int rem = idx & 8191;
      const int ch = rem >> 8, dcol = rem & 255;
      const unsigned* src = (const unsigned*)((op ? kb : qb) + base + (size_t)ch * HW_ + rd * 512) + dcol;
      *(unsigned*)(&pan[op][ch * 520 + dcol * 2]) = *src;
    }
    __syncthreads();
    #pragma unroll
    for (int j8 = 0; j8 < 8; ++j8){
      const int s = j8 * 4 + w;
      const short8 av = *(const short8*)(&pan[0][l31 * 520 + s * 16 + l5 * 8]);
      const short8 bv = *(const short8*)(&pan[1][l31 * 520 + s * 16 + l5 * 8]);
      acc = __builtin_amdgcn_mfma_f32_32x32x16_bf16(av, bv, acc, 0, 0, 0);
    }
  }
  __syncthreads();
  float* red = (float*)pan;
  #pragma unroll
  for (int r = 0; r < 16; ++r) red[w * 1024 + r * 64 + lane] = acc[r];
  __syncthreads();
  #pragma unroll
  for (int q = 0; q < 4; ++q){
    const int fi = q * 256 + t;
    const float v = red[fi] + red[1024 + fi] + red[2048 + fi] + red[3072 + fi];
    const int rr = fi >> 6, ll = fi & 63;
    const int c = (rr & 3) + 8 * (rr >> 2) + 4 * (ll >> 5);   // m101 C-layout
    const int d = ll & 31;
    Gp[(((size_t)ns * 24 + bh) * 32 + c) * 32 + d] = v;
  }
}

// ---------------- k_attn: norms + softmax + M = proj @ attn_bd ----------------
__global__ __launch_bounds__(256)
void k_attn(const float* __restrict__ Gp, const float* __restrict__ qqp,
            const float* __restrict__ kkp, const float* __restrict__ temp,
            const float* __restrict__ proj, float* __restrict__ M)
{
  const int b = blockIdx.x, t = threadIdx.x;
  __shared__ float at[3][32][32];
  __shared__ float ninv[2][C_];
  if (t < 2 * C_){
    const int kind = t / C_, r = t - kind * C_;
    const float* P = kind ? kkp : qqp;
    float s = 0.f;
    #pragma unroll
    for (int ns = 0; ns < NB_; ++ns) s += P[((size_t)b * NB_ + ns) * C_ + r];
    ninv[kind][r] = 1.f / fmaxf(sqrtf(s), 1e-12f);
  }
  __syncthreads();
  for (int idx = t; idx < 3 * 1024; idx += 256){
    const int h = idx >> 10, rem = idx & 1023, cc = rem >> 5, dd = rem & 31;
    float g = 0.f;
    #pragma unroll
    for (int ns = 0; ns < 24; ++ns)
      g += Gp[(((size_t)ns * 24 + b * 3 + h) * 32 + cc) * 32 + dd];
    at[h][cc][dd] = g * ninv[0][h * 32 + cc] * ninv[1][h * 32 + dd] * temp[h];
  }
  __syncthreads();
  if (t < C_){
    const int h = t >> 5, cc = t & 31;
    float m = -1e30f;
    for (int dd = 0; dd < 32; ++dd) m = fmaxf(m, at[h][cc][dd]);
    float s = 0.f;
    for (int dd = 0; dd < 32; ++dd){ const float e = expf(at[h][cc][dd] - m); at[h][cc][dd] = e; s += e; }
    const float inv = 1.f / s;
    for (int dd = 0; dd < 32; ++dd) at[h][cc][dd] *= inv;
  }
  __syncthreads();
  for (int idx = t; idx < C_ * C_; idx += 256){
    const int o = idx / 96, hd = idx - o * 96, h = hd >> 5, dd = hd & 31;
    float m = 0.f;
    #pragma unroll
    for (int cc = 0; cc < 32; ++cc)
      m = fmaf(proj[o * 96 + h * 32 + cc], at[h][cc][dd], m);
    M[(size_t)b * 9216 + idx] = m;
  }
}

extern "C" void kernel_launch(void* const* d_in, const int* in_sizes, int n_in,
                              void* d_out, int out_size, void* d_ws, size_t ws_size,
                              hipStream_t stream)
{
  const float* x     = (const float*)d_in[0];
  const float* y     = (const float*)d_in[1];
  const float* z     = (const float*)d_in[2];
  const float* temp  = (const float*)d_in[3];
  const float* q_pwc = (const float*)d_in[4];
  const float* q_dwc = (const float*)d_in[5];
  const float* k_pwc = (const float*)d_in[6];
  const float* k_dwc = (const float*)d_in[7];
  const float* v_pwc = (const float*)d_in[8];
  const float* v_dwc = (const float*)d_in[9];
  const float* proj  = (const float*)d_in[10];

  // workspace layout
  char* ws = (char*)d_ws;
  unsigned short* qb = (unsigned short*)(ws + 56623104);
  unsigned short* kb = (unsigned short*)(ws + 113246208);
  unsigned short* vb = (unsigned short*)(ws + 169869312);      // end 226,492,416
  float* qqp = (float*)(ws + 226492416);                       // 98,304
  float* kkp = (float*)(ws + 226590720);                       // 98,304
  float* Gp  = (float*)(ws + 4194304);                         // 589,824 (free region)
  float* M   = (float*)(ws + 8388608);                         // 294,912 (free region)
  float* out = (float*)d_out;

  k_conv_all<<<dim3(NB_, B_, 3), 1024, 0, stream>>>(
      x, y, z, q_pwc, k_pwc, v_pwc, q_dwc, k_dwc, v_dwc, qb, kb, vb, qqp, kkp);
  k_gram<<<dim3(24, 24), 256, 0, stream>>>(qb, kb, Gp);
  k_attn<<<B_, 256, 0, stream>>>(Gp, qqp, kkp, temp, proj, M);
  k_gemm<<<dim3(HW_ / 256, B_), 256, 0, stream>>>(vb, M, out);
}

// Round 18
// 281.322 us; speedup vs baseline: 1.4983x; 1.2713x over previous
//
#include <hip/hip_runtime.h>

// CrossAttention MI355X — round 18: byte-exact revert to round 13 (281.7 µs,
// the session best). Rounds 14-17 all regressed on the same failure mode: the
// register allocator targets occupancy the 153KB LDS can never provide and
// spills loop-carried state to scratch (WRITE_SIZE 242-550MB vs 168MB true
// output), regardless of __launch_bounds__ / amdgpu_waves_per_eu hints.
// r13 (768 threads, 12 waves, 84 VGPR) is the proven spill-free configuration.
//  k_conv_all      : q/k/v = in + dw3x3(pw @ in), h in 3-row LDS ring
//  k_gram          : G[b,h] = q @ k^T    (32x32x16 MFMA)
//  k_attn          : norms + softmax + M[b] = proj @ attn_blockdiag
//  k_gemm          : out = M[b] @ v      (f32 direct epilogue)

#define B_  8
#define C_  96
#define W_  192
#define HW_ 36864
#define NB_ 32     // row-bands per image in k_conv (6 rows each)

typedef __attribute__((ext_vector_type(8)))  short short8;
typedef __attribute__((ext_vector_type(4)))  float f32x4;
typedef __attribute__((ext_vector_type(16))) float f32x16;

__device__ __forceinline__ unsigned short f2b(float f){
  unsigned u = __float_as_uint(f);
  u += 0x7fffu + ((u >> 16) & 1u);
  return (unsigned short)(u >> 16);
}
__device__ __forceinline__ float blo(unsigned u){ return __uint_as_float(u << 16); }
__device__ __forceinline__ float bhi(unsigned u){ return __uint_as_float(u & 0xffff0000u); }

// Barrier waiting only on LDS ops (lgkmcnt), not global stores (vmcnt).
// All global->consumer deps here are same-thread register deps.
__device__ __forceinline__ void barrier_lds(){
  asm volatile("s_waitcnt lgkmcnt(0)\n\ts_barrier" ::: "memory");
}

// ---------------- k_conv_all: out = in + dw3x3(pw @ in), h in LDS ring -------
// grid (32 bands, 8 b, 3 conv), block 768 (12 waves), 153KB LDS (1 block/CU).
// GEMM: wave w = (mtg=w%6, ntg=w/6) -> 16 x 96 tile (18 MFMA, 3-reg afrag).
// Dwise: wave owns 8 channels, lanes 0..47 = 4-col groups.
// Per row r: phase A = issue stage-loads(r+1) to regs, row-GEMM -> ring slot;
// phase B = reg->LDS stage-write(r+1) ∥ dwise(r-1).
__global__ __launch_bounds__(768, 1)
void k_conv_all(const float* __restrict__ x0, const float* __restrict__ x1,
                const float* __restrict__ x2,
                const float* __restrict__ pw0, const float* __restrict__ pw1,
                const float* __restrict__ pw2,
                const float* __restrict__ dw0, const float* __restrict__ dw1,
                const float* __restrict__ dw2,
                unsigned short* __restrict__ o0, unsigned short* __restrict__ o1,
                unsigned short* __restrict__ o2,
                float* __restrict__ n0, float* __restrict__ n1)
{
  __shared__ unsigned short xrow[192 * 104];      // 39,936 B  [pix][ch]
  __shared__ unsigned short hring[3][96 * 196];   // 112,896 B [slot][ch][1+col]

  const int t = threadIdx.x, lane = t & 63, wv = t >> 6;
  const int band = blockIdx.x, b = blockIdx.y, cid = blockIdx.z;
  const float* xsrc = (cid == 0) ? x0 : (cid == 1) ? x1 : x2;
  const float* pw   = (cid == 0) ? pw0 : (cid == 1) ? pw1 : pw2;
  const float* dwt  = (cid == 0) ? dw0 : (cid == 1) ? dw1 : dw2;
  unsigned short* outq = (cid == 0) ? o0 : (cid == 1) ? o1 : o2;
  float* nrm = (cid == 0) ? n0 : (cid == 1) ? n1 : nullptr;

  const int r0 = band * 6;
  const int l15 = lane & 15, l4 = lane >> 4;
  const int mtg = wv % 6, ntg = wv / 6;           // ntg 0..1
  const float* xb = xsrc + (size_t)b * C_ * HW_;

  // staging task decomposition: 2304 = 768 x 3 exactly
  int scp[3], spg[3];
  #pragma unroll
  for (int i = 0; i < 3; ++i){
    const int idx = i * 768 + t;
    scp[i] = idx / 48; spg[i] = idx - scp[i] * 48;
  }

  // pw A-frags in registers: single m-tile (16 rows) x 3 k-steps
  short8 afrag[3];
  #pragma unroll
  for (int ks = 0; ks < 3; ++ks){
    const int m = mtg * 16 + l15;
    const float* ap = pw + m * 96 + ks * 32 + l4 * 8;
    const float4 f0 = *(const float4*)ap;
    const float4 f1 = *(const float4*)(ap + 4);
    union { short8 v; unsigned short u[8]; } tmp;
    tmp.u[0]=f2b(f0.x); tmp.u[1]=f2b(f0.y); tmp.u[2]=f2b(f0.z); tmp.u[3]=f2b(f0.w);
    tmp.u[4]=f2b(f1.x); tmp.u[5]=f2b(f1.y); tmp.u[6]=f2b(f1.z); tmp.u[7]=f2b(f1.w);
    afrag[ks] = tmp.v;
  }

  // zero ring once (covers halo cols 0 and 193..195 permanently)
  {
    uint4* p = (uint4*)&hring[0][0];
    for (int i = t; i < 7056; i += 768) p[i] = make_uint4(0,0,0,0);
  }

  float ssq[8];
  #pragma unroll
  for (int i = 0; i < 8; ++i) ssq[i] = 0.f;

  auto stage_write = [&](const float4* fa, const float4* fb){
    #pragma unroll
    for (int i = 0; i < 3; ++i){
      const int pg = spg[i];
      const unsigned pk0 = (unsigned)f2b(fa[i].x) | ((unsigned)f2b(fb[i].x) << 16);
      const unsigned pk1 = (unsigned)f2b(fa[i].y) | ((unsigned)f2b(fb[i].y) << 16);
      const unsigned pk2 = (unsigned)f2b(fa[i].z) | ((unsigned)f2b(fb[i].z) << 16);
      const unsigned pk3 = (unsigned)f2b(fa[i].w) | ((unsigned)f2b(fb[i].w) << 16);
      const int s = (pg >> 1) & 3;                 // XOR-barrel bank spread
      const unsigned a0 = (s & 1) ? pk1 : pk0;
      const unsigned a1 = (s & 1) ? pk0 : pk1;
      const unsigned a2 = (s & 1) ? pk3 : pk2;
      const unsigned a3 = (s & 1) ? pk2 : pk3;
      const unsigned q0 = (s & 2) ? a2 : a0;
      const unsigned q1 = (s & 2) ? a3 : a1;
      const unsigned q2 = (s & 2) ? a0 : a2;
      const unsigned q3 = (s & 2) ? a1 : a3;
      unsigned short* basep = xrow + (4*pg) * 104 + 2*scp[i];
      *(unsigned*)(basep + ((0 ^ s) * 104)) = q0;
      *(unsigned*)(basep + ((1 ^ s) * 104)) = q1;
      *(unsigned*)(basep + ((2 ^ s) * 104)) = q2;
      *(unsigned*)(basep + ((3 ^ s) * 104)) = q3;
    }
  };
  auto stage_load = [&](int rs, float4* fa, float4* fb){
    #pragma unroll
    for (int i = 0; i < 3; ++i){
      const float* xp = xb + (size_t)(2*scp[i]) * HW_ + (size_t)rs * W_ + 4*spg[i];
      fa[i] = *(const float4*)xp;
      fb[i] = *(const float4*)(xp + HW_);
    }
  };

  // prologue: stage row r0-1 synchronously (if in image)
  if (r0 - 1 >= 0){
    float4 fa[3], fb[3];
    stage_load(r0 - 1, fa, fb);
    stage_write(fa, fb);
  }
  barrier_lds();

  #pragma unroll 1
  for (int r = r0 - 1; r <= r0 + 6; ++r){
    const int slot = (r + 3) % 3;
    const int rs = r + 1;
    const bool do_stage = (rs <= r0 + 6) && (rs < 192);
    float4 sfa[3], sfb[3];
    if (do_stage) stage_load(rs, sfa, sfb);   // issue early; consumed in phase B

    // ---- phase A: row GEMM h[96][192] = pw @ xrow  (or zero slot)
    if (r >= 0 && r < 192){
      f32x4 acc[6];
      #pragma unroll
      for (int nt = 0; nt < 6; ++nt){
        acc[nt][0]=0.f; acc[nt][1]=0.f; acc[nt][2]=0.f; acc[nt][3]=0.f;
      }
      #pragma unroll
      for (int ks = 0; ks < 3; ++ks){
        #pragma unroll
        for (int nt = 0; nt < 6; ++nt){
          const short8 bv = *(const short8*)(xrow + (ntg*96 + nt*16 + l15) * 104 + ks*32 + l4*8);
          acc[nt] = __builtin_amdgcn_mfma_f32_16x16x32_bf16(afrag[ks], bv, acc[nt], 0, 0, 0);
        }
      }
      unsigned short* hs = &hring[slot][0];
      #pragma unroll
      for (int nt = 0; nt < 6; ++nt)
        #pragma unroll
        for (int reg = 0; reg < 4; ++reg){
          const int m = mtg*16 + l4*4 + reg;            // out-ch
          const int n = ntg*96 + nt*16 + l15;           // pix col
          hs[m * 196 + 1 + n] = f2b(acc[nt][reg]);
        }
    } else {
      uint4* p = (uint4*)&hring[slot][0];
      for (int i = t; i < 2352; i += 768) p[i] = make_uint4(0,0,0,0);
    }
    barrier_lds();   // ring row r ready; xrow free

    // ---- phase B: stage-write(r+1) ∥ dwise(r-1)
    if (do_stage) stage_write(sfa, sfb);
    if (r - 1 >= r0){
      const int rr = r - 1;
      const unsigned short* h0 = &hring[(rr + 2) % 3][0];   // row rr-1
      const unsigned short* h1 = &hring[(rr + 3) % 3][0];   // row rr
      const unsigned short* h2 = &hring[(rr + 4) % 3][0];   // row rr+1
      if (lane < 48){
        const int g = lane;
        float4 xr_[8];                       // hoisted residual prefetch
        const float* xrp = xb + (size_t)rr * W_ + 4*g;
        #pragma unroll
        for (int cc = 0; cc < 8; ++cc)
          xr_[cc] = *(const float4*)(xrp + (size_t)(wv * 8 + cc) * HW_);
        #pragma unroll
        for (int cc = 0; cc < 8; ++cc){
          const int chs = __builtin_amdgcn_readfirstlane(wv * 8 + cc);
          float wgt[9];
          #pragma unroll
          for (int i = 0; i < 9; ++i) wgt[i] = dwt[chs * 9 + i];   // s_load
          const int rb = chs * 196 + 4 * g;
          float hv[3][6];
          {
            const unsigned short* hp[3] = {h0 + rb, h1 + rb, h2 + rb};
            #pragma unroll
            for (int d = 0; d < 3; ++d){
              const uint2 ua = *(const uint2*)(hp[d]);           // imgcols 4g-1..4g+2
              const unsigned ub = *(const unsigned*)(hp[d] + 4); // imgcols 4g+3,4g+4
              hv[d][0]=blo(ua.x); hv[d][1]=bhi(ua.x); hv[d][2]=blo(ua.y);
              hv[d][3]=bhi(ua.y); hv[d][4]=blo(ub);   hv[d][5]=bhi(ub);
            }
          }
          float o[4] = {xr_[cc].x, xr_[cc].y, xr_[cc].z, xr_[cc].w};
          #pragma unroll
          for (int j = 0; j < 4; ++j){
            float s = o[j];
            #pragma unroll
            for (int d = 0; d < 3; ++d){
              s = fmaf(wgt[d*3+0], hv[d][j],   s);
              s = fmaf(wgt[d*3+1], hv[d][j+1], s);
              s = fmaf(wgt[d*3+2], hv[d][j+2], s);
            }
            o[j] = s;
            ssq[cc] = fmaf(s, s, ssq[cc]);
          }
          const size_t cb = (size_t)(b * C_ + chs) * HW_ + (size_t)rr * W_ + 4*g;
          const unsigned p0 = (unsigned)f2b(o[0]) | ((unsigned)f2b(o[1]) << 16);
          const unsigned p1 = (unsigned)f2b(o[2]) | ((unsigned)f2b(o[3]) << 16);
          *(uint2*)(outq + cb) = make_uint2(p0, p1);
        }
      }
    }
    barrier_lds();   // xrow(r+1) ready; ring slot (r+1)%3 free for overwrite
  }

  if (nrm){
    #pragma unroll
    for (int cc = 0; cc < 8; ++cc){
      float s = ssq[cc];                     // lanes 48..63 contribute 0
      #pragma unroll
      for (int off = 32; off; off >>= 1) s += __shfl_xor(s, off);
      if (lane == 0)
        nrm[((size_t)b * NB_ + band) * C_ + wv * 8 + cc] = s;
    }
  }
}

// ---------------- k_gemm: out[96][36864] = M(96x96,per-b) @ v ----------------
// grid (144, 8), block 256 (4 waves), 2 blocks/CU. v staged transposed
// [pix][104ch] via uint2 loads (4px) + pair-pack + XOR-barrel writes.
__global__ __launch_bounds__(256, 2)
void k_gemm(const unsigned short* __restrict__ Bsrc, const float* __restrict__ Asrc,
            float* __restrict__ Dst)
{
  __shared__ unsigned short xT[256 * 104];   // 53,248 B  [pix][ch]
  __shared__ unsigned short aw[96 * 104];    // 19,968 B  [m][k]
  const int t = threadIdx.x;
  const int b = blockIdx.y;
  const int p0 = blockIdx.x * 256;
  const int lane = t & 63, w = t >> 6;
  const int l15 = lane & 15, l4 = lane >> 4;

  const float* Ab = Asrc + b * C_ * C_;
  #pragma unroll
  for (int j = 0; j < 18; ++j){
    const int pi = j * 256 + t;
    const int row = pi / 48, c2 = (pi - row * 48) * 2;
    const float a0 = Ab[row * 96 + c2], a1 = Ab[row * 96 + c2 + 1];
    *(unsigned*)(aw + row * 104 + c2) = (unsigned)f2b(a0) | ((unsigned)f2b(a1) << 16);
  }
  #pragma unroll 1
  for (int i = 0; i < 12; ++i){
    const int idx = i * 256 + t;
    const int cp = idx >> 6, pg = idx & 63;
    const unsigned short* vp = Bsrc + (size_t)b * C_ * HW_ + (size_t)(2*cp) * HW_ + p0 + 4*pg;
    const uint2 ua = *(const uint2*)vp;          // 4 px of ch 2cp
    const uint2 ub = *(const uint2*)(vp + HW_);  // 4 px of ch 2cp+1
    const unsigned pk0 = (ua.x & 0xffffu) | (ub.x << 16);
    const unsigned pk1 = (ua.x >> 16)     | (ub.x & 0xffff0000u);
    const unsigned pk2 = (ua.y & 0xffffu) | (ub.y << 16);
    const unsigned pk3 = (ua.y >> 16)     | (ub.y & 0xffff0000u);
    const int s = (pg >> 1) & 3;
    const unsigned a0 = (s & 1) ? pk1 : pk0;
    const unsigned a1 = (s & 1) ? pk0 : pk1;
    const unsigned a2 = (s & 1) ? pk3 : pk2;
    const unsigned a3 = (s & 1) ? pk2 : pk3;
    const unsigned q0 = (s & 2) ? a2 : a0;
    const unsigned q1 = (s & 2) ? a3 : a1;
    const unsigned q2 = (s & 2) ? a0 : a2;
    const unsigned q3 = (s & 2) ? a1 : a3;
    unsigned short* basep = xT + (4*pg) * 104 + 2*cp;
    *(unsigned*)(basep + ((0 ^ s) * 104)) = q0;
    *(unsigned*)(basep + ((1 ^ s) * 104)) = q1;
    *(unsigned*)(basep + ((2 ^ s) * 104)) = q2;
    *(unsigned*)(basep + ((3 ^ s) * 104)) = q3;
  }
  __syncthreads();

  f32x4 acc[6][4];
  #pragma unroll
  for (int i = 0; i < 6; ++i)
    #pragma unroll
    for (int j = 0; j < 4; ++j){ acc[i][j][0]=0.f; acc[i][j][1]=0.f; acc[i][j][2]=0.f; acc[i][j][3]=0.f; }

  #pragma unroll
  for (int ks = 0; ks < 3; ++ks){
    short8 a[6];
    #pragma unroll
    for (int mt = 0; mt < 6; ++mt)
      a[mt] = *(const short8*)(aw + (mt * 16 + l15) * 104 + ks * 32 + l4 * 8);
    #pragma unroll
    for (int nt = 0; nt < 4; ++nt){
      const short8 bv = *(const short8*)(xT + (w * 64 + nt * 16 + l15) * 104 + ks * 32 + l4 * 8);
      #pragma unroll
      for (int mt = 0; mt < 6; ++mt)
        acc[mt][nt] = __builtin_amdgcn_mfma_f32_16x16x32_bf16(a[mt], bv, acc[mt][nt], 0, 0, 0);
    }
  }

  float* D = Dst + (size_t)b * C_ * HW_ + p0;
  #pragma unroll
  for (int mt = 0; mt < 6; ++mt)
    #pragma unroll
    for (int nt = 0; nt < 4; ++nt)
      #pragma unroll
      for (int r = 0; r < 4; ++r)
        D[(size_t)(mt * 16 + l4 * 4 + r) * HW_ + w * 64 + nt * 16 + l15] = acc[mt][nt][r];
}

// ---------------- k_gram: G[b,h] = q_bh @ k_bh^T ----------------
__global__ __launch_bounds__(256, 2)
void k_gram(const unsigned short* __restrict__ qb, const unsigned short* __restrict__ kb,
            float* __restrict__ Gp)
{
  __shared__ unsigned short pan[2][32 * 520];   // 66,560 B
  const int t = threadIdx.x, lane = t & 63, w = t >> 6;
  const int ns = blockIdx.x, bh = blockIdx.y;
  const int b = bh / 3, h = bh - b * 3;
  const size_t base = ((size_t)b * C_ + h * 32) * HW_ + ns * 1536;
  const int l31 = lane & 31, l5 = lane >> 5;

  f32x16 acc;
  #pragma unroll
  for (int r = 0; r < 16; ++r) acc[r] = 0.f;

  #pragma unroll 1
  for (int rd = 0; rd < 3; ++rd){
    __syncthreads();
    #pragma unroll 8
    for (int j = 0; j < 64; ++j){
      const int idx = j * 256 + t;
      const int op = idx >> 13;
      const int rem = idx & 8191;
      const int ch = rem >> 8, dcol = rem & 255;
      const unsigned* src = (const unsigned*)((op ? kb : qb) + base + (size_t)ch * HW_ + rd * 512) + dcol;
      *(unsigned*)(&pan[op][ch * 520 + dcol * 2]) = *src;
    }
    __syncthreads();
    #pragma unroll
    for (int j8 = 0; j8 < 8; ++j8){
      const int s = j8 * 4 + w;
      const short8 av = *(const short8*)(&pan[0][l31 * 520 + s * 16 + l5 * 8]);
      const short8 bv = *(const short8*)(&pan[1][l31 * 520 + s * 16 + l5 * 8]);
      acc = __builtin_amdgcn_mfma_f32_32x32x16_bf16(av, bv, acc, 0, 0, 0);
    }
  }
  __syncthreads();
  float* red = (float*)pan;
  #pragma unroll
  for (int r = 0; r < 16; ++r) red[w * 1024 + r * 64 + lane] = acc[r];
  __syncthreads();
  #pragma unroll
  for (int q = 0; q < 4; ++q){
    const int fi = q * 256 + t;
    const float v = red[fi] + red[1024 + fi] + red[2048 + fi] + red[3072 + fi];
    const int rr = fi >> 6, ll = fi & 63;
    const int c = (rr & 3) + 8 * (rr >> 2) + 4 * (ll >> 5);   // m101 C-layout
    const int d = ll & 31;
    Gp[(((size_t)ns * 24 + bh) * 32 + c) * 32 + d] = v;
  }
}

// ---------------- k_attn: norms + softmax + M = proj @ attn_bd ----------------
__global__ __launch_bounds__(256)
void k_attn(const float* __restrict__ Gp, const float* __restrict__ qqp,
            const float* __restrict__ kkp, const float* __restrict__ temp,
            const float* __restrict__ proj, float* __restrict__ M)
{
  const int b = blockIdx.x, t = threadIdx.x;
  __shared__ float at[3][32][32];
  __shared__ float ninv[2][C_];
  if (t < 2 * C_){
    const int kind = t / C_, r = t - kind * C_;
    const float* P = kind ? kkp : qqp;
    float s = 0.f;
    #pragma unroll
    for (int ns = 0; ns < NB_; ++ns) s += P[((size_t)b * NB_ + ns) * C_ + r];
    ninv[kind][r] = 1.f / fmaxf(sqrtf(s), 1e-12f);
  }
  __syncthreads();
  for (int idx = t; idx < 3 * 1024; idx += 256){
    const int h = idx >> 10, rem = idx & 1023, cc = rem >> 5, dd = rem & 31;
    float g = 0.f;
    #pragma unroll
    for (int ns = 0; ns < 24; ++ns)
      g += Gp[(((size_t)ns * 24 + b * 3 + h) * 32 + cc) * 32 + dd];
    at[h][cc][dd] = g * ninv[0][h * 32 + cc] * ninv[1][h * 32 + dd] * temp[h];
  }
  __syncthreads();
  if (t < C_){
    const int h = t >> 5, cc = t & 31;
    float m = -1e30f;
    for (int dd = 0; dd < 32; ++dd) m = fmaxf(m, at[h][cc][dd]);
    float s = 0.f;
    for (int dd = 0; dd < 32; ++dd){ const float e = expf(at[h][cc][dd] - m); at[h][cc][dd] = e; s += e; }
    const float inv = 1.f / s;
    for (int dd = 0; dd < 32; ++dd) at[h][cc][dd] *= inv;
  }
  __syncthreads();
  for (int idx = t; idx < C_ * C_; idx += 256){
    const int o = idx / 96, hd = idx - o * 96, h = hd >> 5, dd = hd & 31;
    float m = 0.f;
    #pragma unroll
    for (int cc = 0; cc < 32; ++cc)
      m = fmaf(proj[o * 96 + h * 32 + cc], at[h][cc][dd], m);
    M[(size_t)b * 9216 + idx] = m;
  }
}

extern "C" void kernel_launch(void* const* d_in, const int* in_sizes, int n_in,
                              void* d_out, int out_size, void* d_ws, size_t ws_size,
                              hipStream_t stream)
{
  const float* x     = (const float*)d_in[0];
  const float* y     = (const float*)d_in[1];
  const float* z     = (const float*)d_in[2];
  const float* temp  = (const float*)d_in[3];
  const float* q_pwc = (const float*)d_in[4];
  const float* q_dwc = (const float*)d_in[5];
  const float* k_pwc = (const float*)d_in[6];
  const float* k_dwc = (const float*)d_in[7];
  const float* v_pwc = (const float*)d_in[8];
  const float* v_dwc = (const float*)d_in[9];
  const float* proj  = (const float*)d_in[10];

  // workspace layout
  char* ws = (char*)d_ws;
  unsigned short* qb = (unsigned short*)(ws + 56623104);
  unsigned short* kb = (unsigned short*)(ws + 113246208);
  unsigned short* vb = (unsigned short*)(ws + 169869312);      // end 226,492,416
  float* qqp = (float*)(ws + 226492416);                       // 98,304
  float* kkp = (float*)(ws + 226590720);                       // 98,304
  float* Gp  = (float*)(ws + 4194304);                         // 589,824 (free region)
  float* M   = (float*)(ws + 8388608);                         // 294,912 (free region)
  float* out = (float*)d_out;

  k_conv_all<<<dim3(NB_, B_, 3), 768, 0, stream>>>(
      x, y, z, q_pwc, k_pwc, v_pwc, q_dwc, k_dwc, v_dwc, qb, kb, vb, qqp, kkp);
  k_gram<<<dim3(24, 24), 256, 0, stream>>>(qb, kb, Gp);
  k_attn<<<B_, 256, 0, stream>>>(Gp, qqp, kkp, temp, proj, M);
  k_gemm<<<dim3(HW_ / 256, B_), 256, 0, stream>>>(vb, M, out);
}

// Round 19
// 274.624 us; speedup vs baseline: 1.5349x; 1.0244x over previous
//
#include <hip/hip_runtime.h>

// CrossAttention MI355X — round 19: r18 (= r13 best, 281.3 µs) + k_gram
// n-split 24->18 (432 blocks <= 512 co-resident slots -> no straggler wave;
// each block does 4 rounds of the same 512-px panel instead of 3).
// k_conv_all / k_gemm / workspace byte-identical to the proven r18 state.
//  k_conv_all      : q/k/v = in + dw3x3(pw @ in), h in 3-row LDS ring
//  k_gram          : G[b,h] = q @ k^T    (32x32x16 MFMA)
//  k_attn          : norms + softmax + M[b] = proj @ attn_blockdiag
//  k_gemm          : out = M[b] @ v      (f32 direct epilogue)

#define B_  8
#define C_  96
#define W_  192
#define HW_ 36864
#define NB_ 32     // row-bands per image in k_conv (6 rows each)
#define NS_ 18     // k_gram n-splits (432 blocks -> single co-resident wave)

typedef __attribute__((ext_vector_type(8)))  short short8;
typedef __attribute__((ext_vector_type(4)))  float f32x4;
typedef __attribute__((ext_vector_type(16))) float f32x16;

__device__ __forceinline__ unsigned short f2b(float f){
  unsigned u = __float_as_uint(f);
  u += 0x7fffu + ((u >> 16) & 1u);
  return (unsigned short)(u >> 16);
}
__device__ __forceinline__ float blo(unsigned u){ return __uint_as_float(u << 16); }
__device__ __forceinline__ float bhi(unsigned u){ return __uint_as_float(u & 0xffff0000u); }

// Barrier waiting only on LDS ops (lgkmcnt), not global stores (vmcnt).
// All global->consumer deps here are same-thread register deps.
__device__ __forceinline__ void barrier_lds(){
  asm volatile("s_waitcnt lgkmcnt(0)\n\ts_barrier" ::: "memory");
}

// ---------------- k_conv_all: out = in + dw3x3(pw @ in), h in LDS ring -------
// grid (32 bands, 8 b, 3 conv), block 768 (12 waves), 153KB LDS (1 block/CU).
// GEMM: wave w = (mtg=w%6, ntg=w/6) -> 16 x 96 tile (18 MFMA, 3-reg afrag).
// Dwise: wave owns 8 channels, lanes 0..47 = 4-col groups.
// Per row r: phase A = issue stage-loads(r+1) to regs, row-GEMM -> ring slot;
// phase B = reg->LDS stage-write(r+1) ∥ dwise(r-1).
__global__ __launch_bounds__(768, 1)
void k_conv_all(const float* __restrict__ x0, const float* __restrict__ x1,
                const float* __restrict__ x2,
                const float* __restrict__ pw0, const float* __restrict__ pw1,
                const float* __restrict__ pw2,
                const float* __restrict__ dw0, const float* __restrict__ dw1,
                const float* __restrict__ dw2,
                unsigned short* __restrict__ o0, unsigned short* __restrict__ o1,
                unsigned short* __restrict__ o2,
                float* __restrict__ n0, float* __restrict__ n1)
{
  __shared__ unsigned short xrow[192 * 104];      // 39,936 B  [pix][ch]
  __shared__ unsigned short hring[3][96 * 196];   // 112,896 B [slot][ch][1+col]

  const int t = threadIdx.x, lane = t & 63, wv = t >> 6;
  const int band = blockIdx.x, b = blockIdx.y, cid = blockIdx.z;
  const float* xsrc = (cid == 0) ? x0 : (cid == 1) ? x1 : x2;
  const float* pw   = (cid == 0) ? pw0 : (cid == 1) ? pw1 : pw2;
  const float* dwt  = (cid == 0) ? dw0 : (cid == 1) ? dw1 : dw2;
  unsigned short* outq = (cid == 0) ? o0 : (cid == 1) ? o1 : o2;
  float* nrm = (cid == 0) ? n0 : (cid == 1) ? n1 : nullptr;

  const int r0 = band * 6;
  const int l15 = lane & 15, l4 = lane >> 4;
  const int mtg = wv % 6, ntg = wv / 6;           // ntg 0..1
  const float* xb = xsrc + (size_t)b * C_ * HW_;

  // staging task decomposition: 2304 = 768 x 3 exactly
  int scp[3], spg[3];
  #pragma unroll
  for (int i = 0; i < 3; ++i){
    const int idx = i * 768 + t;
    scp[i] = idx / 48; spg[i] = idx - scp[i] * 48;
  }

  // pw A-frags in registers: single m-tile (16 rows) x 3 k-steps
  short8 afrag[3];
  #pragma unroll
  for (int ks = 0; ks < 3; ++ks){
    const int m = mtg * 16 + l15;
    const float* ap = pw + m * 96 + ks * 32 + l4 * 8;
    const float4 f0 = *(const float4*)ap;
    const float4 f1 = *(const float4*)(ap + 4);
    union { short8 v; unsigned short u[8]; } tmp;
    tmp.u[0]=f2b(f0.x); tmp.u[1]=f2b(f0.y); tmp.u[2]=f2b(f0.z); tmp.u[3]=f2b(f0.w);
    tmp.u[4]=f2b(f1.x); tmp.u[5]=f2b(f1.y); tmp.u[6]=f2b(f1.z); tmp.u[7]=f2b(f1.w);
    afrag[ks] = tmp.v;
  }

  // zero ring once (covers halo cols 0 and 193..195 permanently)
  {
    uint4* p = (uint4*)&hring[0][0];
    for (int i = t; i < 7056; i += 768) p[i] = make_uint4(0,0,0,0);
  }

  float ssq[8];
  #pragma unroll
  for (int i = 0; i < 8; ++i) ssq[i] = 0.f;

  auto stage_write = [&](const float4* fa, const float4* fb){
    #pragma unroll
    for (int i = 0; i < 3; ++i){
      const int pg = spg[i];
      const unsigned pk0 = (unsigned)f2b(fa[i].x) | ((unsigned)f2b(fb[i].x) << 16);
      const unsigned pk1 = (unsigned)f2b(fa[i].y) | ((unsigned)f2b(fb[i].y) << 16);
      const unsigned pk2 = (unsigned)f2b(fa[i].z) | ((unsigned)f2b(fb[i].z) << 16);
      const unsigned pk3 = (unsigned)f2b(fa[i].w) | ((unsigned)f2b(fb[i].w) << 16);
      const int s = (pg >> 1) & 3;                 // XOR-barrel bank spread
      const unsigned a0 = (s & 1) ? pk1 : pk0;
      const unsigned a1 = (s & 1) ? pk0 : pk1;
      const unsigned a2 = (s & 1) ? pk3 : pk2;
      const unsigned a3 = (s & 1) ? pk2 : pk3;
      const unsigned q0 = (s & 2) ? a2 : a0;
      const unsigned q1 = (s & 2) ? a3 : a1;
      const unsigned q2 = (s & 2) ? a0 : a2;
      const unsigned q3 = (s & 2) ? a1 : a3;
      unsigned short* basep = xrow + (4*pg) * 104 + 2*scp[i];
      *(unsigned*)(basep + ((0 ^ s) * 104)) = q0;
      *(unsigned*)(basep + ((1 ^ s) * 104)) = q1;
      *(unsigned*)(basep + ((2 ^ s) * 104)) = q2;
      *(unsigned*)(basep + ((3 ^ s) * 104)) = q3;
    }
  };
  auto stage_load = [&](int rs, float4* fa, float4* fb){
    #pragma unroll
    for (int i = 0; i < 3; ++i){
      const float* xp = xb + (size_t)(2*scp[i]) * HW_ + (size_t)rs * W_ + 4*spg[i];
      fa[i] = *(const float4*)xp;
      fb[i] = *(const float4*)(xp + HW_);
    }
  };

  // prologue: stage row r0-1 synchronously (if in image)
  if (r0 - 1 >= 0){
    float4 fa[3], fb[3];
    stage_load(r0 - 1, fa, fb);
    stage_write(fa, fb);
  }
  barrier_lds();

  #pragma unroll 1
  for (int r = r0 - 1; r <= r0 + 6; ++r){
    const int slot = (r + 3) % 3;
    const int rs = r + 1;
    const bool do_stage = (rs <= r0 + 6) && (rs < 192);
    float4 sfa[3], sfb[3];
    if (do_stage) stage_load(rs, sfa, sfb);   // issue early; consumed in phase B

    // ---- phase A: row GEMM h[96][192] = pw @ xrow  (or zero slot)
    if (r >= 0 && r < 192){
      f32x4 acc[6];
      #pragma unroll
      for (int nt = 0; nt < 6; ++nt){
        acc[nt][0]=0.f; acc[nt][1]=0.f; acc[nt][2]=0.f; acc[nt][3]=0.f;
      }
      #pragma unroll
      for (int ks = 0; ks < 3; ++ks){
        #pragma unroll
        for (int nt = 0; nt < 6; ++nt){
          const short8 bv = *(const short8*)(xrow + (ntg*96 + nt*16 + l15) * 104 + ks*32 + l4*8);
          acc[nt] = __builtin_amdgcn_mfma_f32_16x16x32_bf16(afrag[ks], bv, acc[nt], 0, 0, 0);
        }
      }
      unsigned short* hs = &hring[slot][0];
      #pragma unroll
      for (int nt = 0; nt < 6; ++nt)
        #pragma unroll
        for (int reg = 0; reg < 4; ++reg){
          const int m = mtg*16 + l4*4 + reg;            // out-ch
          const int n = ntg*96 + nt*16 + l15;           // pix col
          hs[m * 196 + 1 + n] = f2b(acc[nt][reg]);
        }
    } else {
      uint4* p = (uint4*)&hring[slot][0];
      for (int i = t; i < 2352; i += 768) p[i] = make_uint4(0,0,0,0);
    }
    barrier_lds();   // ring row r ready; xrow free

    // ---- phase B: stage-write(r+1) ∥ dwise(r-1)
    if (do_stage) stage_write(sfa, sfb);
    if (r - 1 >= r0){
      const int rr = r - 1;
      const unsigned short* h0 = &hring[(rr + 2) % 3][0];   // row rr-1
      const unsigned short* h1 = &hring[(rr + 3) % 3][0];   // row rr
      const unsigned short* h2 = &hring[(rr + 4) % 3][0];   // row rr+1
      if (lane < 48){
        const int g = lane;
        float4 xr_[8];                       // hoisted residual prefetch
        const float* xrp = xb + (size_t)rr * W_ + 4*g;
        #pragma unroll
        for (int cc = 0; cc < 8; ++cc)
          xr_[cc] = *(const float4*)(xrp + (size_t)(wv * 8 + cc) * HW_);
        #pragma unroll
        for (int cc = 0; cc < 8; ++cc){
          const int chs = __builtin_amdgcn_readfirstlane(wv * 8 + cc);
          float wgt[9];
          #pragma unroll
          for (int i = 0; i < 9; ++i) wgt[i] = dwt[chs * 9 + i];   // s_load
          const int rb = chs * 196 + 4 * g;
          float hv[3][6];
          {
            const unsigned short* hp[3] = {h0 + rb, h1 + rb, h2 + rb};
            #pragma unroll
            for (int d = 0; d < 3; ++d){
              const uint2 ua = *(const uint2*)(hp[d]);           // imgcols 4g-1..4g+2
              const unsigned ub = *(const unsigned*)(hp[d] + 4); // imgcols 4g+3,4g+4
              hv[d][0]=blo(ua.x); hv[d][1]=bhi(ua.x); hv[d][2]=blo(ua.y);
              hv[d][3]=bhi(ua.y); hv[d][4]=blo(ub);   hv[d][5]=bhi(ub);
            }
          }
          float o[4] = {xr_[cc].x, xr_[cc].y, xr_[cc].z, xr_[cc].w};
          #pragma unroll
          for (int j = 0; j < 4; ++j){
            float s = o[j];
            #pragma unroll
            for (int d = 0; d < 3; ++d){
              s = fmaf(wgt[d*3+0], hv[d][j],   s);
              s = fmaf(wgt[d*3+1], hv[d][j+1], s);
              s = fmaf(wgt[d*3+2], hv[d][j+2], s);
            }
            o[j] = s;
            ssq[cc] = fmaf(s, s, ssq[cc]);
          }
          const size_t cb = (size_t)(b * C_ + chs) * HW_ + (size_t)rr * W_ + 4*g;
          const unsigned p0 = (unsigned)f2b(o[0]) | ((unsigned)f2b(o[1]) << 16);
          const unsigned p1 = (unsigned)f2b(o[2]) | ((unsigned)f2b(o[3]) << 16);
          *(uint2*)(outq + cb) = make_uint2(p0, p1);
        }
      }
    }
    barrier_lds();   // xrow(r+1) ready; ring slot (r+1)%3 free for overwrite
  }

  if (nrm){
    #pragma unroll
    for (int cc = 0; cc < 8; ++cc){
      float s = ssq[cc];                     // lanes 48..63 contribute 0
      #pragma unroll
      for (int off = 32; off; off >>= 1) s += __shfl_xor(s, off);
      if (lane == 0)
        nrm[((size_t)b * NB_ + band) * C_ + wv * 8 + cc] = s;
    }
  }
}

// ---------------- k_gemm: out[96][36864] = M(96x96,per-b) @ v ----------------
// grid (144, 8), block 256 (4 waves), 2 blocks/CU. v staged transposed
// [pix][104ch] via uint2 loads (4px) + pair-pack + XOR-barrel writes.
__global__ __launch_bounds__(256, 2)
void k_gemm(const unsigned short* __restrict__ Bsrc, const float* __restrict__ Asrc,
            float* __restrict__ Dst)
{
  __shared__ unsigned short xT[256 * 104];   // 53,248 B  [pix][ch]
  __shared__ unsigned short aw[96 * 104];    // 19,968 B  [m][k]
  const int t = threadIdx.x;
  const int b = blockIdx.y;
  const int p0 = blockIdx.x * 256;
  const int lane = t & 63, w = t >> 6;
  const int l15 = lane & 15, l4 = lane >> 4;

  const float* Ab = Asrc + b * C_ * C_;
  #pragma unroll
  for (int j = 0; j < 18; ++j){
    const int pi = j * 256 + t;
    const int row = pi / 48, c2 = (pi - row * 48) * 2;
    const float a0 = Ab[row * 96 + c2], a1 = Ab[row * 96 + c2 + 1];
    *(unsigned*)(aw + row * 104 + c2) = (unsigned)f2b(a0) | ((unsigned)f2b(a1) << 16);
  }
  #pragma unroll 1
  for (int i = 0; i < 12; ++i){
    const int idx = i * 256 + t;
    const int cp = idx >> 6, pg = idx & 63;
    const unsigned short* vp = Bsrc + (size_t)b * C_ * HW_ + (size_t)(2*cp) * HW_ + p0 + 4*pg;
    const uint2 ua = *(const uint2*)vp;          // 4 px of ch 2cp
    const uint2 ub = *(const uint2*)(vp + HW_);  // 4 px of ch 2cp+1
    const unsigned pk0 = (ua.x & 0xffffu) | (ub.x << 16);
    const unsigned pk1 = (ua.x >> 16)     | (ub.x & 0xffff0000u);
    const unsigned pk2 = (ua.y & 0xffffu) | (ub.y << 16);
    const unsigned pk3 = (ua.y >> 16)     | (ub.y & 0xffff0000u);
    const int s = (pg >> 1) & 3;
    const unsigned a0 = (s & 1) ? pk1 : pk0;
    const unsigned a1 = (s & 1) ? pk0 : pk1;
    const unsigned a2 = (s & 1) ? pk3 : pk2;
    const unsigned a3 = (s & 1) ? pk2 : pk3;
    const unsigned q0 = (s & 2) ? a2 : a0;
    const unsigned q1 = (s & 2) ? a3 : a1;
    const unsigned q2 = (s & 2) ? a0 : a2;
    const unsigned q3 = (s & 2) ? a1 : a3;
    unsigned short* basep = xT + (4*pg) * 104 + 2*cp;
    *(unsigned*)(basep + ((0 ^ s) * 104)) = q0;
    *(unsigned*)(basep + ((1 ^ s) * 104)) = q1;
    *(unsigned*)(basep + ((2 ^ s) * 104)) = q2;
    *(unsigned*)(basep + ((3 ^ s) * 104)) = q3;
  }
  __syncthreads();

  f32x4 acc[6][4];
  #pragma unroll
  for (int i = 0; i < 6; ++i)
    #pragma unroll
    for (int j = 0; j < 4; ++j){ acc[i][j][0]=0.f; acc[i][j][1]=0.f; acc[i][j][2]=0.f; acc[i][j][3]=0.f; }

  #pragma unroll
  for (int ks = 0; ks < 3; ++ks){
    short8 a[6];
    #pragma unroll
    for (int mt = 0; mt < 6; ++mt)
      a[mt] = *(const short8*)(aw + (mt * 16 + l15) * 104 + ks * 32 + l4 * 8);
    #pragma unroll
    for (int nt = 0; nt < 4; ++nt){
      const short8 bv = *(const short8*)(xT + (w * 64 + nt * 16 + l15) * 104 + ks * 32 + l4 * 8);
      #pragma unroll
      for (int mt = 0; mt < 6; ++mt)
        acc[mt][nt] = __builtin_amdgcn_mfma_f32_16x16x32_bf16(a[mt], bv, acc[mt][nt], 0, 0, 0);
    }
  }

  float* D = Dst + (size_t)b * C_ * HW_ + p0;
  #pragma unroll
  for (int mt = 0; mt < 6; ++mt)
    #pragma unroll
    for (int nt = 0; nt < 4; ++nt)
      #pragma unroll
      for (int r = 0; r < 4; ++r)
        D[(size_t)(mt * 16 + l4 * 4 + r) * HW_ + w * 64 + nt * 16 + l15] = acc[mt][nt][r];
}

// ---------------- k_gram: G[b,h] = q_bh @ k_bh^T ----------------
// grid (18 ns, 24 bh), block 256 (4 waves): 432 blocks <= 512 co-resident
// slots (2 blocks/CU at 66.5KB LDS) -> no straggler wave. Per block: 2048-px
// chunk, 4 rounds of 512-px panels [32ch][520px] (straight-copy staging).
__global__ __launch_bounds__(256, 2)
void k_gram(const unsigned short* __restrict__ qb, const unsigned short* __restrict__ kb,
            float* __restrict__ Gp)
{
  __shared__ unsigned short pan[2][32 * 520];   // 66,560 B
  const int t = threadIdx.x, lane = t & 63, w = t >> 6;
  const int ns = blockIdx.x, bh = blockIdx.y;
  const int b = bh / 3, h = bh - b * 3;
  const size_t base = ((size_t)b * C_ + h * 32) * HW_ + ns * 2048;
  const int l31 = lane & 31, l5 = lane >> 5;

  f32x16 acc;
  #pragma unroll
  for (int r = 0; r < 16; ++r) acc[r] = 0.f;

  #pragma unroll 1
  for (int rd = 0; rd < 4; ++rd){
    __syncthreads();
    #pragma unroll 8
    for (int j = 0; j < 64; ++j){
      const int idx = j * 256 + t;
      const int op = idx >> 13;
      const int rem = idx & 8191;
      const int ch = rem >> 8, dcol = rem & 255;
      const unsigned* src = (const unsigned*)((op ? kb : qb) + base + (size_t)ch * HW_ + rd * 512) + dcol;
      *(unsigned*)(&pan[op][ch * 520 + dcol * 2]) = *src;
    }
    __syncthreads();
    #pragma unroll
    for (int j8 = 0; j8 < 8; ++j8){
      const int s = j8 * 4 + w;
      const short8 av = *(const short8*)(&pan[0][l31 * 520 + s * 16 + l5 * 8]);
      const short8 bv = *(const short8*)(&pan[1][l31 * 520 + s * 16 + l5 * 8]);
      acc = __builtin_amdgcn_mfma_f32_32x32x16_bf16(av, bv, acc, 0, 0, 0);
    }
  }
  __syncthreads();
  float* red = (float*)pan;
  #pragma unroll
  for (int r = 0; r < 16; ++r) red[w * 1024 + r * 64 + lane] = acc[r];
  __syncthreads();
  #pragma unroll
  for (int q = 0; q < 4; ++q){
    const int fi = q * 256 + t;
    const float v = red[fi] + red[1024 + fi] + red[2048 + fi] + red[3072 + fi];
    const int rr = fi >> 6, ll = fi & 63;
    const int c = (rr & 3) + 8 * (rr >> 2) + 4 * (ll >> 5);   // m101 C-layout
    const int d = ll & 31;
    Gp[(((size_t)ns * 24 + bh) * 32 + c) * 32 + d] = v;
  }
}

// ---------------- k_attn: norms + softmax + M = proj @ attn_bd ----------------
__global__ __launch_bounds__(256)
void k_attn(const float* __restrict__ Gp, const float* __restrict__ qqp,
            const float* __restrict__ kkp, const float* __restrict__ temp,
            const float* __restrict__ proj, float* __restrict__ M)
{
  const int b = blockIdx.x, t = threadIdx.x;
  __shared__ float at[3][32][32];
  __shared__ float ninv[2][C_];
  if (t < 2 * C_){
    const int kind = t / C_, r = t - kind * C_;
    const float* P = kind ? kkp : qqp;
    float s = 0.f;
    #pragma unroll
    for (int ns = 0; ns < NB_; ++ns) s += P[((size_t)b * NB_ + ns) * C_ + r];
    ninv[kind][r] = 1.f / fmaxf(sqrtf(s), 1e-12f);
  }
  __syncthreads();
  for (int idx = t; idx < 3 * 1024; idx += 256){
    const int h = idx >> 10, rem = idx & 1023, cc = rem >> 5, dd = rem & 31;
    float g = 0.f;
    #pragma unroll
    for (int ns = 0; ns < NS_; ++ns)
      g += Gp[(((size_t)ns * 24 + b * 3 + h) * 32 + cc) * 32 + dd];
    at[h][cc][dd] = g * ninv[0][h * 32 + cc] * ninv[1][h * 32 + dd] * temp[h];
  }
  __syncthreads();
  if (t < C_){
    const int h = t >> 5, cc = t & 31;
    float m = -1e30f;
    for (int dd = 0; dd < 32; ++dd) m = fmaxf(m, at[h][cc][dd]);
    float s = 0.f;
    for (int dd = 0; dd < 32; ++dd){ const float e = expf(at[h][cc][dd] - m); at[h][cc][dd] = e; s += e; }
    const float inv = 1.f / s;
    for (int dd = 0; dd < 32; ++dd) at[h][cc][dd] *= inv;
  }
  __syncthreads();
  for (int idx = t; idx < C_ * C_; idx += 256){
    const int o = idx / 96, hd = idx - o * 96, h = hd >> 5, dd = hd & 31;
    float m = 0.f;
    #pragma unroll
    for (int cc = 0; cc < 32; ++cc)
      m = fmaf(proj[o * 96 + h * 32 + cc], at[h][cc][dd], m);
    M[(size_t)b * 9216 + idx] = m;
  }
}

extern "C" void kernel_launch(void* const* d_in, const int* in_sizes, int n_in,
                              void* d_out, int out_size, void* d_ws, size_t ws_size,
                              hipStream_t stream)
{
  const float* x     = (const float*)d_in[0];
  const float* y     = (const float*)d_in[1];
  const float* z     = (const float*)d_in[2];
  const float* temp  = (const float*)d_in[3];
  const float* q_pwc = (const float*)d_in[4];
  const float* q_dwc = (const float*)d_in[5];
  const float* k_pwc = (const float*)d_in[6];
  const float* k_dwc = (const float*)d_in[7];
  const float* v_pwc = (const float*)d_in[8];
  const float* v_dwc = (const float*)d_in[9];
  const float* proj  = (const float*)d_in[10];

  // workspace layout
  char* ws = (char*)d_ws;
  unsigned short* qb = (unsigned short*)(ws + 56623104);
  unsigned short* kb = (unsigned short*)(ws + 113246208);
  unsigned short* vb = (unsigned short*)(ws + 169869312);      // end 226,492,416
  float* qqp = (float*)(ws + 226492416);                       // 98,304
  float* kkp = (float*)(ws + 226590720);                       // 98,304
  float* Gp  = (float*)(ws + 4194304);                         // 1,769,472 (free region)
  float* M   = (float*)(ws + 8388608);                         // 294,912 (free region)
  float* out = (float*)d_out;

  k_conv_all<<<dim3(NB_, B_, 3), 768, 0, stream>>>(
      x, y, z, q_pwc, k_pwc, v_pwc, q_dwc, k_dwc, v_dwc, qb, kb, vb, qqp, kkp);
  k_gram<<<dim3(NS_, 24), 256, 0, stream>>>(qb, kb, Gp);
  k_attn<<<B_, 256, 0, stream>>>(Gp, qqp, kkp, temp, proj, M);
  k_gemm<<<dim3(HW_ / 256, B_), 256, 0, stream>>>(vb, M, out);
}

// Round 20
// 270.386 us; speedup vs baseline: 1.5589x; 1.0157x over previous
//
#include <hip/hip_runtime.h>

// CrossAttention MI355X — round 20: r19 (274.6 µs) + k_gemm retiled to 128
// px/block (46.6KB LDS -> 3 blocks/CU; grid 2304 = exactly 3.0 co-resident
// waves -> no straggler; 12 waves/CU for the latency-bound staging phase).
// k_conv_all / k_gram / k_attn byte-identical to r19.
//  k_conv_all      : q/k/v = in + dw3x3(pw @ in), h in 3-row LDS ring
//  k_gram          : G[b,h] = q @ k^T    (32x32x16 MFMA, 18 n-splits)
//  k_attn          : norms + softmax + M[b] = proj @ attn_blockdiag
//  k_gemm          : out = M[b] @ v      (f32 direct epilogue, 128 px/block)

#define B_  8
#define C_  96
#define W_  192
#define HW_ 36864
#define NB_ 32     // row-bands per image in k_conv (6 rows each)
#define NS_ 18     // k_gram n-splits (432 blocks -> single co-resident wave)

typedef __attribute__((ext_vector_type(8)))  short short8;
typedef __attribute__((ext_vector_type(4)))  float f32x4;
typedef __attribute__((ext_vector_type(16))) float f32x16;

__device__ __forceinline__ unsigned short f2b(float f){
  unsigned u = __float_as_uint(f);
  u += 0x7fffu + ((u >> 16) & 1u);
  return (unsigned short)(u >> 16);
}
__device__ __forceinline__ float blo(unsigned u){ return __uint_as_float(u << 16); }
__device__ __forceinline__ float bhi(unsigned u){ return __uint_as_float(u & 0xffff0000u); }

// Barrier waiting only on LDS ops (lgkmcnt), not global stores (vmcnt).
// All global->consumer deps here are same-thread register deps.
__device__ __forceinline__ void barrier_lds(){
  asm volatile("s_waitcnt lgkmcnt(0)\n\ts_barrier" ::: "memory");
}

// ---------------- k_conv_all: out = in + dw3x3(pw @ in), h in LDS ring -------
// grid (32 bands, 8 b, 3 conv), block 768 (12 waves), 153KB LDS (1 block/CU).
// GEMM: wave w = (mtg=w%6, ntg=w/6) -> 16 x 96 tile (18 MFMA, 3-reg afrag).
// Dwise: wave owns 8 channels, lanes 0..47 = 4-col groups.
// Per row r: phase A = issue stage-loads(r+1) to regs, row-GEMM -> ring slot;
// phase B = reg->LDS stage-write(r+1) ∥ dwise(r-1).
__global__ __launch_bounds__(768, 1)
void k_conv_all(const float* __restrict__ x0, const float* __restrict__ x1,
                const float* __restrict__ x2,
                const float* __restrict__ pw0, const float* __restrict__ pw1,
                const float* __restrict__ pw2,
                const float* __restrict__ dw0, const float* __restrict__ dw1,
                const float* __restrict__ dw2,
                unsigned short* __restrict__ o0, unsigned short* __restrict__ o1,
                unsigned short* __restrict__ o2,
                float* __restrict__ n0, float* __restrict__ n1)
{
  __shared__ unsigned short xrow[192 * 104];      // 39,936 B  [pix][ch]
  __shared__ unsigned short hring[3][96 * 196];   // 112,896 B [slot][ch][1+col]

  const int t = threadIdx.x, lane = t & 63, wv = t >> 6;
  const int band = blockIdx.x, b = blockIdx.y, cid = blockIdx.z;
  const float* xsrc = (cid == 0) ? x0 : (cid == 1) ? x1 : x2;
  const float* pw   = (cid == 0) ? pw0 : (cid == 1) ? pw1 : pw2;
  const float* dwt  = (cid == 0) ? dw0 : (cid == 1) ? dw1 : dw2;
  unsigned short* outq = (cid == 0) ? o0 : (cid == 1) ? o1 : o2;
  float* nrm = (cid == 0) ? n0 : (cid == 1) ? n1 : nullptr;

  const int r0 = band * 6;
  const int l15 = lane & 15, l4 = lane >> 4;
  const int mtg = wv % 6, ntg = wv / 6;           // ntg 0..1
  const float* xb = xsrc + (size_t)b * C_ * HW_;

  // staging task decomposition: 2304 = 768 x 3 exactly
  int scp[3], spg[3];
  #pragma unroll
  for (int i = 0; i < 3; ++i){
    const int idx = i * 768 + t;
    scp[i] = idx / 48; spg[i] = idx - scp[i] * 48;
  }

  // pw A-frags in registers: single m-tile (16 rows) x 3 k-steps
  short8 afrag[3];
  #pragma unroll
  for (int ks = 0; ks < 3; ++ks){
    const int m = mtg * 16 + l15;
    const float* ap = pw + m * 96 + ks * 32 + l4 * 8;
    const float4 f0 = *(const float4*)ap;
    const float4 f1 = *(const float4*)(ap + 4);
    union { short8 v; unsigned short u[8]; } tmp;
    tmp.u[0]=f2b(f0.x); tmp.u[1]=f2b(f0.y); tmp.u[2]=f2b(f0.z); tmp.u[3]=f2b(f0.w);
    tmp.u[4]=f2b(f1.x); tmp.u[5]=f2b(f1.y); tmp.u[6]=f2b(f1.z); tmp.u[7]=f2b(f1.w);
    afrag[ks] = tmp.v;
  }

  // zero ring once (covers halo cols 0 and 193..195 permanently)
  {
    uint4* p = (uint4*)&hring[0][0];
    for (int i = t; i < 7056; i += 768) p[i] = make_uint4(0,0,0,0);
  }

  float ssq[8];
  #pragma unroll
  for (int i = 0; i < 8; ++i) ssq[i] = 0.f;

  auto stage_write = [&](const float4* fa, const float4* fb){
    #pragma unroll
    for (int i = 0; i < 3; ++i){
      const int pg = spg[i];
      const unsigned pk0 = (unsigned)f2b(fa[i].x) | ((unsigned)f2b(fb[i].x) << 16);
      const unsigned pk1 = (unsigned)f2b(fa[i].y) | ((unsigned)f2b(fb[i].y) << 16);
      const unsigned pk2 = (unsigned)f2b(fa[i].z) | ((unsigned)f2b(fb[i].z) << 16);
      const unsigned pk3 = (unsigned)f2b(fa[i].w) | ((unsigned)f2b(fb[i].w) << 16);
      const int s = (pg >> 1) & 3;                 // XOR-barrel bank spread
      const unsigned a0 = (s & 1) ? pk1 : pk0;
      const unsigned a1 = (s & 1) ? pk0 : pk1;
      const unsigned a2 = (s & 1) ? pk3 : pk2;
      const unsigned a3 = (s & 1) ? pk2 : pk3;
      const unsigned q0 = (s & 2) ? a2 : a0;
      const unsigned q1 = (s & 2) ? a3 : a1;
      const unsigned q2 = (s & 2) ? a0 : a2;
      const unsigned q3 = (s & 2) ? a1 : a3;
      unsigned short* basep = xrow + (4*pg) * 104 + 2*scp[i];
      *(unsigned*)(basep + ((0 ^ s) * 104)) = q0;
      *(unsigned*)(basep + ((1 ^ s) * 104)) = q1;
      *(unsigned*)(basep + ((2 ^ s) * 104)) = q2;
      *(unsigned*)(basep + ((3 ^ s) * 104)) = q3;
    }
  };
  auto stage_load = [&](int rs, float4* fa, float4* fb){
    #pragma unroll
    for (int i = 0; i < 3; ++i){
      const float* xp = xb + (size_t)(2*scp[i]) * HW_ + (size_t)rs * W_ + 4*spg[i];
      fa[i] = *(const float4*)xp;
      fb[i] = *(const float4*)(xp + HW_);
    }
  };

  // prologue: stage row r0-1 synchronously (if in image)
  if (r0 - 1 >= 0){
    float4 fa[3], fb[3];
    stage_load(r0 - 1, fa, fb);
    stage_write(fa, fb);
  }
  barrier_lds();

  #pragma unroll 1
  for (int r = r0 - 1; r <= r0 + 6; ++r){
    const int slot = (r + 3) % 3;
    const int rs = r + 1;
    const bool do_stage = (rs <= r0 + 6) && (rs < 192);
    float4 sfa[3], sfb[3];
    if (do_stage) stage_load(rs, sfa, sfb);   // issue early; consumed in phase B

    // ---- phase A: row GEMM h[96][192] = pw @ xrow  (or zero slot)
    if (r >= 0 && r < 192){
      f32x4 acc[6];
      #pragma unroll
      for (int nt = 0; nt < 6; ++nt){
        acc[nt][0]=0.f; acc[nt][1]=0.f; acc[nt][2]=0.f; acc[nt][3]=0.f;
      }
      #pragma unroll
      for (int ks = 0; ks < 3; ++ks){
        #pragma unroll
        for (int nt = 0; nt < 6; ++nt){
          const short8 bv = *(const short8*)(xrow + (ntg*96 + nt*16 + l15) * 104 + ks*32 + l4*8);
          acc[nt] = __builtin_amdgcn_mfma_f32_16x16x32_bf16(afrag[ks], bv, acc[nt], 0, 0, 0);
        }
      }
      unsigned short* hs = &hring[slot][0];
      #pragma unroll
      for (int nt = 0; nt < 6; ++nt)
        #pragma unroll
        for (int reg = 0; reg < 4; ++reg){
          const int m = mtg*16 + l4*4 + reg;            // out-ch
          const int n = ntg*96 + nt*16 + l15;           // pix col
          hs[m * 196 + 1 + n] = f2b(acc[nt][reg]);
        }
    } else {
      uint4* p = (uint4*)&hring[slot][0];
      for (int i = t; i < 2352; i += 768) p[i] = make_uint4(0,0,0,0);
    }
    barrier_lds();   // ring row r ready; xrow free

    // ---- phase B: stage-write(r+1) ∥ dwise(r-1)
    if (do_stage) stage_write(sfa, sfb);
    if (r - 1 >= r0){
      const int rr = r - 1;
      const unsigned short* h0 = &hring[(rr + 2) % 3][0];   // row rr-1
      const unsigned short* h1 = &hring[(rr + 3) % 3][0];   // row rr
      const unsigned short* h2 = &hring[(rr + 4) % 3][0];   // row rr+1
      if (lane < 48){
        const int g = lane;
        float4 xr_[8];                       // hoisted residual prefetch
        const float* xrp = xb + (size_t)rr * W_ + 4*g;
        #pragma unroll
        for (int cc = 0; cc < 8; ++cc)
          xr_[cc] = *(const float4*)(xrp + (size_t)(wv * 8 + cc) * HW_);
        #pragma unroll
        for (int cc = 0; cc < 8; ++cc){
          const int chs = __builtin_amdgcn_readfirstlane(wv * 8 + cc);
          float wgt[9];
          #pragma unroll
          for (int i = 0; i < 9; ++i) wgt[i] = dwt[chs * 9 + i];   // s_load
          const int rb = chs * 196 + 4 * g;
          float hv[3][6];
          {
            const unsigned short* hp[3] = {h0 + rb, h1 + rb, h2 + rb};
            #pragma unroll
            for (int d = 0; d < 3; ++d){
              const uint2 ua = *(const uint2*)(hp[d]);           // imgcols 4g-1..4g+2
              const unsigned ub = *(const unsigned*)(hp[d] + 4); // imgcols 4g+3,4g+4
              hv[d][0]=blo(ua.x); hv[d][1]=bhi(ua.x); hv[d][2]=blo(ua.y);
              hv[d][3]=bhi(ua.y); hv[d][4]=blo(ub);   hv[d][5]=bhi(ub);
            }
          }
          float o[4] = {xr_[cc].x, xr_[cc].y, xr_[cc].z, xr_[cc].w};
          #pragma unroll
          for (int j = 0; j < 4; ++j){
            float s = o[j];
            #pragma unroll
            for (int d = 0; d < 3; ++d){
              s = fmaf(wgt[d*3+0], hv[d][j],   s);
              s = fmaf(wgt[d*3+1], hv[d][j+1], s);
              s = fmaf(wgt[d*3+2], hv[d][j+2], s);
            }
            o[j] = s;
            ssq[cc] = fmaf(s, s, ssq[cc]);
          }
          const size_t cb = (size_t)(b * C_ + chs) * HW_ + (size_t)rr * W_ + 4*g;
          const unsigned p0 = (unsigned)f2b(o[0]) | ((unsigned)f2b(o[1]) << 16);
          const unsigned p1 = (unsigned)f2b(o[2]) | ((unsigned)f2b(o[3]) << 16);
          *(uint2*)(outq + cb) = make_uint2(p0, p1);
        }
      }
    }
    barrier_lds();   // xrow(r+1) ready; ring slot (r+1)%3 free for overwrite
  }

  if (nrm){
    #pragma unroll
    for (int cc = 0; cc < 8; ++cc){
      float s = ssq[cc];                     // lanes 48..63 contribute 0
      #pragma unroll
      for (int off = 32; off; off >>= 1) s += __shfl_xor(s, off);
      if (lane == 0)
        nrm[((size_t)b * NB_ + band) * C_ + wv * 8 + cc] = s;
    }
  }
}

// ---------------- k_gemm: out[96][36864] = M(96x96,per-b) @ v ----------------
// grid (288, 8), block 256 (4 waves), 3 blocks/CU (46.6KB LDS): 2304 blocks =
// exactly 3.0 co-resident waves. Wave w owns pixels [w*32, w*32+32).
// v staged transposed [pix][104ch] via uint2 loads + pair-pack + XOR-barrel.
__global__ __launch_bounds__(256, 3)
void k_gemm(const unsigned short* __restrict__ Bsrc, const float* __restrict__ Asrc,
            float* __restrict__ Dst)
{
  __shared__ unsigned short xT[128 * 104];   // 26,624 B  [pix][ch]
  __shared__ unsigned short aw[96 * 104];    // 19,968 B  [m][k]
  const int t = threadIdx.x;
  const int b = blockIdx.y;
  const int p0 = blockIdx.x * 128;
  const int lane = t & 63, w = t >> 6;
  const int l15 = lane & 15, l4 = lane >> 4;

  const float* Ab = Asrc + b * C_ * C_;
  #pragma unroll
  for (int j = 0; j < 18; ++j){
    const int pi = j * 256 + t;
    const int row = pi / 48, c2 = (pi - row * 48) * 2;
    const float a0 = Ab[row * 96 + c2], a1 = Ab[row * 96 + c2 + 1];
    *(unsigned*)(aw + row * 104 + c2) = (unsigned)f2b(a0) | ((unsigned)f2b(a1) << 16);
  }
  // stage v tile transposed: 1536 tasks = 48 ch-pairs x 32 pixel-quads
  #pragma unroll 1
  for (int i = 0; i < 6; ++i){
    const int idx = i * 256 + t;
    const int cp = idx >> 5, pg = idx & 31;
    const unsigned short* vp = Bsrc + (size_t)b * C_ * HW_ + (size_t)(2*cp) * HW_ + p0 + 4*pg;
    const uint2 ua = *(const uint2*)vp;          // 4 px of ch 2cp
    const uint2 ub = *(const uint2*)(vp + HW_);  // 4 px of ch 2cp+1
    const unsigned pk0 = (ua.x & 0xffffu) | (ub.x << 16);
    const unsigned pk1 = (ua.x >> 16)     | (ub.x & 0xffff0000u);
    const unsigned pk2 = (ua.y & 0xffffu) | (ub.y << 16);
    const unsigned pk3 = (ua.y >> 16)     | (ub.y & 0xffff0000u);
    const int s = (pg >> 1) & 3;
    const unsigned a0 = (s & 1) ? pk1 : pk0;
    const unsigned a1 = (s & 1) ? pk0 : pk1;
    const unsigned a2 = (s & 1) ? pk3 : pk2;
    const unsigned a3 = (s & 1) ? pk2 : pk3;
    const unsigned q0 = (s & 2) ? a2 : a0;
    const unsigned q1 = (s & 2) ? a3 : a1;
    const unsigned q2 = (s & 2) ? a0 : a2;
    const unsigned q3 = (s & 2) ? a1 : a3;
    unsigned short* basep = xT + (4*pg) * 104 + 2*cp;
    *(unsigned*)(basep + ((0 ^ s) * 104)) = q0;
    *(unsigned*)(basep + ((1 ^ s) * 104)) = q1;
    *(unsigned*)(basep + ((2 ^ s) * 104)) = q2;
    *(unsigned*)(basep + ((3 ^ s) * 104)) = q3;
  }
  __syncthreads();

  f32x4 acc[6][2];
  #pragma unroll
  for (int i = 0; i < 6; ++i)
    #pragma unroll
    for (int j = 0; j < 2; ++j){ acc[i][j][0]=0.f; acc[i][j][1]=0.f; acc[i][j][2]=0.f; acc[i][j][3]=0.f; }

  #pragma unroll
  for (int ks = 0; ks < 3; ++ks){
    short8 a[6];
    #pragma unroll
    for (int mt = 0; mt < 6; ++mt)
      a[mt] = *(const short8*)(aw + (mt * 16 + l15) * 104 + ks * 32 + l4 * 8);
    #pragma unroll
    for (int nt = 0; nt < 2; ++nt){
      const short8 bv = *(const short8*)(xT + (w * 32 + nt * 16 + l15) * 104 + ks * 32 + l4 * 8);
      #pragma unroll
      for (int mt = 0; mt < 6; ++mt)
        acc[mt][nt] = __builtin_amdgcn_mfma_f32_16x16x32_bf16(a[mt], bv, acc[mt][nt], 0, 0, 0);
    }
  }

  float* D = Dst + (size_t)b * C_ * HW_ + p0;
  #pragma unroll
  for (int mt = 0; mt < 6; ++mt)
    #pragma unroll
    for (int nt = 0; nt < 2; ++nt)
      #pragma unroll
      for (int r = 0; r < 4; ++r)
        D[(size_t)(mt * 16 + l4 * 4 + r) * HW_ + w * 32 + nt * 16 + l15] = acc[mt][nt][r];
}

// ---------------- k_gram: G[b,h] = q_bh @ k_bh^T ----------------
// grid (18 ns, 24 bh), block 256 (4 waves): 432 blocks <= 512 co-resident
// slots (2 blocks/CU at 66.5KB LDS) -> no straggler wave. Per block: 2048-px
// chunk, 4 rounds of 512-px panels [32ch][520px] (straight-copy staging).
__global__ __launch_bounds__(256, 2)
void k_gram(const unsigned short* __restrict__ qb, const unsigned short* __restrict__ kb,
            float* __restrict__ Gp)
{
  __shared__ unsigned short pan[2][32 * 520];   // 66,560 B
  const int t = threadIdx.x, lane = t & 63, w = t >> 6;
  const int ns = blockIdx.x, bh = blockIdx.y;
  const int b = bh / 3, h = bh - b * 3;
  const size_t base = ((size_t)b * C_ + h * 32) * HW_ + ns * 2048;
  const int l31 = lane & 31, l5 = lane >> 5;

  f32x16 acc;
  #pragma unroll
  for (int r = 0; r < 16; ++r) acc[r] = 0.f;

  #pragma unroll 1
  for (int rd = 0; rd < 4; ++rd){
    __syncthreads();
    #pragma unroll 8
    for (int j = 0; j < 64; ++j){
      const int idx = j * 256 + t;
      const int op = idx >> 13;
      const int rem = idx & 8191;
      const int ch = rem >> 8, dcol = rem & 255;
      const unsigned* src = (const unsigned*)((op ? kb : qb) + base + (size_t)ch * HW_ + rd * 512) + dcol;
      *(unsigned*)(&pan[op][ch * 520 + dcol * 2]) = *src;
    }
    __syncthreads();
    #pragma unroll
    for (int j8 = 0; j8 < 8; ++j8){
      const int s = j8 * 4 + w;
      const short8 av = *(const short8*)(&pan[0][l31 * 520 + s * 16 + l5 * 8]);
      const short8 bv = *(const short8*)(&pan[1][l31 * 520 + s * 16 + l5 * 8]);
      acc = __builtin_amdgcn_mfma_f32_32x32x16_bf16(av, bv, acc, 0, 0, 0);
    }
  }
  __syncthreads();
  float* red = (float*)pan;
  #pragma unroll
  for (int r = 0; r < 16; ++r) red[w * 1024 + r * 64 + lane] = acc[r];
  __syncthreads();
  #pragma unroll
  for (int q = 0; q < 4; ++q){
    const int fi = q * 256 + t;
    const float v = red[fi] + red[1024 + fi] + red[2048 + fi] + red[3072 + fi];
    const int rr = fi >> 6, ll = fi & 63;
    const int c = (rr & 3) + 8 * (rr >> 2) + 4 * (ll >> 5);   // m101 C-layout
    const int d = ll & 31;
    Gp[(((size_t)ns * 24 + bh) * 32 + c) * 32 + d] = v;
  }
}

// ---------------- k_attn: norms + softmax + M = proj @ attn_bd ----------------
__global__ __launch_bounds__(256)
void k_attn(const float* __restrict__ Gp, const float* __restrict__ qqp,
            const float* __restrict__ kkp, const float* __restrict__ temp,
            const float* __restrict__ proj, float* __restrict__ M)
{
  const int b = blockIdx.x, t = threadIdx.x;
  __shared__ float at[3][32][32];
  __shared__ float ninv[2][C_];
  if (t < 2 * C_){
    const int kind = t / C_, r = t - kind * C_;
    const float* P = kind ? kkp : qqp;
    float s = 0.f;
    #pragma unroll
    for (int ns = 0; ns < NB_; ++ns) s += P[((size_t)b * NB_ + ns) * C_ + r];
    ninv[kind][r] = 1.f / fmaxf(sqrtf(s), 1e-12f);
  }
  __syncthreads();
  for (int idx = t; idx < 3 * 1024; idx += 256){
    const int h = idx >> 10, rem = idx & 1023, cc = rem >> 5, dd = rem & 31;
    float g = 0.f;
    #pragma unroll
    for (int ns = 0; ns < NS_; ++ns)
      g += Gp[(((size_t)ns * 24 + b * 3 + h) * 32 + cc) * 32 + dd];
    at[h][cc][dd] = g * ninv[0][h * 32 + cc] * ninv[1][h * 32 + dd] * temp[h];
  }
  __syncthreads();
  if (t < C_){
    const int h = t >> 5, cc = t & 31;
    float m = -1e30f;
    for (int dd = 0; dd < 32; ++dd) m = fmaxf(m, at[h][cc][dd]);
    float s = 0.f;
    for (int dd = 0; dd < 32; ++dd){ const float e = expf(at[h][cc][dd] - m); at[h][cc][dd] = e; s += e; }
    const float inv = 1.f / s;
    for (int dd = 0; dd < 32; ++dd) at[h][cc][dd] *= inv;
  }
  __syncthreads();
  for (int idx = t; idx < C_ * C_; idx += 256){
    const int o = idx / 96, hd = idx - o * 96, h = hd >> 5, dd = hd & 31;
    float m = 0.f;
    #pragma unroll
    for (int cc = 0; cc < 32; ++cc)
      m = fmaf(proj[o * 96 + h * 32 + cc], at[h][cc][dd], m);
    M[(size_t)b * 9216 + idx] = m;
  }
}

extern "C" void kernel_launch(void* const* d_in, const int* in_sizes, int n_in,
                              void* d_out, int out_size, void* d_ws, size_t ws_size,
                              hipStream_t stream)
{
  const float* x     = (const float*)d_in[0];
  const float* y     = (const float*)d_in[1];
  const float* z     = (const float*)d_in[2];
  const float* temp  = (const float*)d_in[3];
  const float* q_pwc = (const float*)d_in[4];
  const float* q_dwc = (const float*)d_in[5];
  const float* k_pwc = (const float*)d_in[6];
  const float* k_dwc = (const float*)d_in[7];
  const float* v_pwc = (const float*)d_in[8];
  const float* v_dwc = (const float*)d_in[9];
  const float* proj  = (const float*)d_in[10];

  // workspace layout
  char* ws = (char*)d_ws;
  unsigned short* qb = (unsigned short*)(ws + 56623104);
  unsigned short* kb = (unsigned short*)(ws + 113246208);
  unsigned short* vb = (unsigned short*)(ws + 169869312);      // end 226,492,416
  float* qqp = (float*)(ws + 226492416);                       // 98,304
  float* kkp = (float*)(ws + 226590720);                       // 98,304
  float* Gp  = (float*)(ws + 4194304);                         // 1,769,472 (free region)
  float* M   = (float*)(ws + 8388608);                         // 294,912 (free region)
  float* out = (float*)d_out;

  k_conv_all<<<dim3(NB_, B_, 3), 768, 0, stream>>>(
      x, y, z, q_pwc, k_pwc, v_pwc, q_dwc, k_dwc, v_dwc, qb, kb, vb, qqp, kkp);
  k_gram<<<dim3(NS_, 24), 256, 0, stream>>>(qb, kb, Gp);
  k_attn<<<B_, 256, 0, stream>>>(Gp, qqp, kkp, temp, proj, M);
  k_gemm<<<dim3(HW_ / 128, B_), 256, 0, stream>>>(vb, M, out);
}